// Round 3
// baseline (669.680 us; speedup 1.0000x reference)
//
#include <hip/hip_runtime.h>
#include <hip/hip_bf16.h>
#include <stdint.h>

// MLAAttention on MI355X (gfx950).
// B=4 T=4096 D=1024 H=16 M=64 Dh=64. All inputs f32 (mask int32), output f32.
// R3: latgemm atomics removed (private per-chunk f32 partials + reduce kernel),
//     split-K 16 chunks, double-buffered LDS staging.

#define DEV static __device__ __forceinline__

using short8 = __attribute__((ext_vector_type(8))) short;
using f32x4  = __attribute__((ext_vector_type(4))) float;

#define ZERO4 (f32x4){0.f, 0.f, 0.f, 0.f}

DEV float bf2f(unsigned short u) {
  union { unsigned int i; float f; } c; c.i = ((unsigned int)u) << 16; return c.f;
}
DEV unsigned short f2bf(float f) {
  __hip_bfloat16 h = __float2bfloat16(f);
  unsigned short u; __builtin_memcpy(&u, &h, 2); return u;
}
DEV f32x4 mfma16(short8 a, short8 b, f32x4 c) {
  return __builtin_amdgcn_mfma_f32_16x16x32_bf16(a, b, c, 0, 0, 0);
}
#define GLOAD_LDS16(G, L) __builtin_amdgcn_global_load_lds( \
    (const __attribute__((address_space(1))) void*)(G),     \
    (__attribute__((address_space(3))) void*)(L), 16, 0, 0)

// ---------------------------------------------------------------- convert
__global__ void cvt_bf16(const float* __restrict__ src,
                         __hip_bfloat16* __restrict__ dst, int n) {
  int i = (blockIdx.x * blockDim.x + threadIdx.x) * 4;
  if (i >= n) return;
  const float4 v = *(const float4*)(src + i);
  ushort4 o;
  o.x = f2bf(v.x); o.y = f2bf(v.y); o.z = f2bf(v.z); o.w = f2bf(v.w);
  *(ushort4*)(dst + i) = o;
}

// ---------------------------------------------------------------- GEMM 128x128
// C[M,N] = A[M,K] @ Bt[N,K]^T, bf16 in, f32 acc. m97 structure.
// MODE: 0 = f32 normal; 1 = bf16 normal; 2 = bf16 normal + bf16 transposed;
//       3 = bf16 transposed only.
// ROPE: apply rotary (pairs along n; t = m&4095, d = n&63) to acc before stores.
// Transposed layout: Ct[((m>>12)*16 + (n>>6))*64 + (n&63)][t = m&4095]  (bf16)
template<int MODE, int ROPE>
__global__ __launch_bounds__(256)
void gemm128(const __hip_bfloat16* __restrict__ A,
             const __hip_bfloat16* __restrict__ Bt,
             void* __restrict__ Cout, __hip_bfloat16* __restrict__ Ct,
             const float* __restrict__ cosT, const float* __restrict__ sinT,
             int M, int N, int K) {
  __shared__ __hip_bfloat16 As[128 * 64];
  __shared__ __hip_bfloat16 Bs[128 * 64];
  const int tid = threadIdx.x;
  const int w = tid >> 6, l = tid & 63;
  const int rowA0 = blockIdx.x * 128;
  const int colB0 = blockIdx.y * 128;
  const int srow = w * 8 + (l >> 3);
  const int skk  = (l & 7) * 8;
  const __hip_bfloat16* Ab = A  + (size_t)(rowA0 + srow) * K + skk;
  const __hip_bfloat16* Bb = Bt + (size_t)(colB0 + srow) * K + skk;
  f32x4 acc[4][4];
#pragma unroll
  for (int i = 0; i < 4; ++i)
#pragma unroll
    for (int j = 0; j < 4; ++j) acc[i][j] = ZERO4;
  const int wr = (w >> 1) * 64, wc = (w & 1) * 64;
  for (int k0 = 0; k0 < K; k0 += 64) {
    __syncthreads();
#pragma unroll
    for (int i = 0; i < 4; ++i) {
      GLOAD_LDS16(Ab + (size_t)(i * 32) * K + k0, &As[i * 2048 + w * 512]);
      GLOAD_LDS16(Bb + (size_t)(i * 32) * K + k0, &Bs[i * 2048 + w * 512]);
    }
    __syncthreads();
#pragma unroll
    for (int s = 0; s < 2; ++s) {
      short8 fa[4], fb[4];
#pragma unroll
      for (int i = 0; i < 4; ++i)
        fa[i] = *(const short8*)&As[(wr + i * 16 + (l & 15)) * 64 + s * 32 + (l >> 4) * 8];
#pragma unroll
      for (int j = 0; j < 4; ++j)
        fb[j] = *(const short8*)&Bs[(wc + j * 16 + (l & 15)) * 64 + s * 32 + (l >> 4) * 8];
#pragma unroll
      for (int i = 0; i < 4; ++i)
#pragma unroll
        for (int j = 0; j < 4; ++j)
          acc[i][j] = mfma16(fa[i], fb[j], acc[i][j]);
    }
  }
  const int r0 = rowA0 + wr + (l >> 4) * 4;   // global row (m) base, +i*16+r
  const int c0 = colB0 + wc + (l & 15);       // global col (n), +j*16
  if (ROPE) {
#pragma unroll
    for (int i = 0; i < 4; ++i)
#pragma unroll
      for (int j = 0; j < 4; ++j)
#pragma unroll
        for (int r = 0; r < 4; ++r) {
          const int m = r0 + i * 16 + r;
          const int n = c0 + j * 16;
          const int t = m & 4095, d = n & 63;
          const float c = cosT[t * 64 + d];
          const float s = sinT[t * 64 + d];
          const float v = acc[i][j][r];
          const float other = __shfl_xor(v, 1, 64);
          acc[i][j][r] = v * c + ((n & 1) ? other : -other) * s;
        }
  }
  if (MODE <= 2) {
#pragma unroll
    for (int i = 0; i < 4; ++i)
#pragma unroll
      for (int j = 0; j < 4; ++j)
#pragma unroll
        for (int r = 0; r < 4; ++r) {
          const size_t idx = (size_t)(r0 + i * 16 + r) * N + (c0 + j * 16);
          if (MODE == 0) ((float*)Cout)[idx] = acc[i][j][r];
          else ((__hip_bfloat16*)Cout)[idx] = __float2bfloat16(acc[i][j][r]);
        }
  }
  if (MODE >= 2) {
#pragma unroll
    for (int i = 0; i < 4; ++i)
#pragma unroll
      for (int j = 0; j < 4; ++j) {
        const int m0 = r0 + i * 16;           // 4 contiguous t per lane
        const int n  = c0 + j * 16;
        const size_t row = (size_t)(((m0 >> 12) * 16 + (n >> 6)) * 64 + (n & 63));
        ushort4 pk;
        pk.x = f2bf(acc[i][j][0]); pk.y = f2bf(acc[i][j][1]);
        pk.z = f2bf(acc[i][j][2]); pk.w = f2bf(acc[i][j][3]);
        *(ushort4*)&Ct[row * 4096 + (m0 & 4095)] = pk;
      }
  }
}

// ---------------------------------------------------------------- stage1 stats
__global__ __launch_bounds__(256)
void stage1_stats(const __hip_bfloat16* __restrict__ kmat,  // [B,T,H,64] (roped)
                  const float* __restrict__ latent,          // [H,64,64]
                  const int* __restrict__ mask,              // [B*T]
                  float* __restrict__ pmax, float* __restrict__ psum) {
  __shared__ __hip_bfloat16 kt[64][64];
  __shared__ float rmx[256], rsm[256];
  const int bh = blockIdx.x, chunk = blockIdx.y;
  const int b = bh >> 4, h = bh & 15;
  const int tid = threadIdx.x, m = tid & 63, g = tid >> 6;
  float latr[64];
#pragma unroll
  for (int d4 = 0; d4 < 16; ++d4) {
    const float4 v = *(const float4*)&latent[((size_t)(h * 64 + m)) * 64 + d4 * 4];
    latr[d4 * 4 + 0] = v.x; latr[d4 * 4 + 1] = v.y;
    latr[d4 * 4 + 2] = v.z; latr[d4 * 4 + 3] = v.w;
  }
  float mx = -3.0e38f, sm = 0.f;
  const int tbase = chunk * 512;
  for (int tt = 0; tt < 512; tt += 64) {
    __syncthreads();
    for (int i = tid; i < 512; i += 256) {
      const int r = i >> 3, o = (i & 7) * 8;
      *(uint4*)&kt[r][o] =
          *(const uint4*)&kmat[((size_t)(b * 4096 + tbase + tt + r) * 16 + h) * 64 + o];
    }
    __syncthreads();
    for (int tl = 0; tl < 16; ++tl) {
      const int t = g * 16 + tl;
      float dot = 0.f;
#pragma unroll
      for (int d8 = 0; d8 < 8; ++d8) {
        const short8 kv = *(const short8*)&kt[t][d8 * 8];
#pragma unroll
        for (int jj = 0; jj < 8; ++jj)
          dot += bf2f((unsigned short)kv[jj]) * latr[d8 * 8 + jj];
      }
      dot *= 0.125f;
      if (mask[b * 4096 + tbase + tt + t] != 0) {
        const float nmx = fmaxf(mx, dot);
        sm = sm * __expf(mx - nmx) + __expf(dot - nmx);
        mx = nmx;
      }
    }
  }
  rmx[tid] = mx; rsm[tid] = sm;
  __syncthreads();
  if (g == 0) {
#pragma unroll
    for (int gg = 1; gg < 4; ++gg) {
      const float omx = rmx[gg * 64 + m], osm = rsm[gg * 64 + m];
      const float nmx = fmaxf(mx, omx);
      sm = sm * __expf(mx - nmx) + osm * __expf(omx - nmx);
      mx = nmx;
    }
    pmax[((size_t)bh * 8 + chunk) * 64 + m] = mx;
    psum[((size_t)bh * 8 + chunk) * 64 + m] = sm;
  }
}

__global__ void stage1_reduce(const float* __restrict__ pmax,
                              const float* __restrict__ psum,
                              float* __restrict__ cmax, float* __restrict__ cinv) {
  const int i = blockIdx.x * 256 + threadIdx.x;
  if (i >= 4096) return;
  const int bh = i >> 6, m = i & 63;
  float mx = -3.0e38f;
#pragma unroll
  for (int c = 0; c < 8; ++c)
    mx = fmaxf(mx, pmax[((size_t)bh * 8 + c) * 64 + m]);
  float sm = 0.f;
#pragma unroll
  for (int c = 0; c < 8; ++c)
    sm += psum[((size_t)bh * 8 + c) * 64 + m] *
          __expf(pmax[((size_t)bh * 8 + c) * 64 + m] - mx);
  cmax[i] = mx;
  cinv[i] = 1.f / sm;
}

// P^T materialization: Pt[bh, m, t] bf16 (coalesced over t = lane)
__global__ __launch_bounds__(256)
void stage1_pvals(const __hip_bfloat16* __restrict__ kmat,
                  const float* __restrict__ latent,
                  const int* __restrict__ mask,
                  const float* __restrict__ cmax, const float* __restrict__ cinv,
                  __hip_bfloat16* __restrict__ Pt) {
  const int bh = blockIdx.x >> 4;
  const int t = (blockIdx.x & 15) * 256 + threadIdx.x;
  const int b = bh >> 4, h = bh & 15;
  float kr[64];
  {
    const __hip_bfloat16* kp = &kmat[((size_t)(b * 4096 + t) * 16 + h) * 64];
#pragma unroll
    for (int d8 = 0; d8 < 8; ++d8) {
      const short8 kv = *(const short8*)&kp[d8 * 8];
#pragma unroll
      for (int jj = 0; jj < 8; ++jj) kr[d8 * 8 + jj] = bf2f((unsigned short)kv[jj]);
    }
  }
  const bool live = (mask[b * 4096 + t] != 0);
  for (int m = 0; m < 64; ++m) {
    const float* lp = &latent[((size_t)h * 64 + m) * 64];
    float dot = 0.f;
#pragma unroll
    for (int dd = 0; dd < 64; ++dd) dot += kr[dd] * lp[dd];
    dot *= 0.125f;
    const float p = live ? __expf(dot - cmax[bh * 64 + m]) * cinv[bh * 64 + m] : 0.f;
    Pt[((size_t)bh * 64 + m) * 4096 + t] = __float2bfloat16(p);
  }
}

// ---------------------------------------------------------------- latent GEMM v3
// k_lat_part[m,d] = sum_t Pt[m,t]*kT[d,t]; v_latT_part[d,m] = sum_t vT[d,t]*Pt[m,t].
// grid (bh=64, chunk=16 of 256 t); per-(chunk,bh) private f32 partials, no atomics.
// Double-buffered LDS staging (2-phase: stage next || compute current).
__global__ __launch_bounds__(256)
void latgemm3(const __hip_bfloat16* __restrict__ Pt,
              const __hip_bfloat16* __restrict__ kT,
              const __hip_bfloat16* __restrict__ vT,
              float* __restrict__ partials) {   // [chunk][bh][8192]
  __shared__ __hip_bfloat16 Ps[2][64 * 64];
  __shared__ __hip_bfloat16 Ks[2][64 * 64];
  __shared__ __hip_bfloat16 Vs[2][64 * 64];
  const int bh = blockIdx.x, chunk = blockIdx.y;
  const int tid = threadIdx.x, w = tid >> 6, l = tid & 63;
  const int wr = w >> 1, wc = w & 1;
  f32x4 ak[2][2], av[2][2];
#pragma unroll
  for (int i = 0; i < 2; ++i)
#pragma unroll
    for (int j = 0; j < 2; ++j) { ak[i][j] = ZERO4; av[i][j] = ZERO4; }
  const int srow = l >> 3, scol = (l & 7) * 8;
  const size_t pbase = (size_t)bh * 64 * 4096;

#define LG_STAGE(st, buf)                                                      \
  {                                                                            \
    const int tb = chunk * 256 + (st) * 64;                                    \
    _Pragma("unroll")                                                          \
    for (int c = 0; c < 2; ++c) {                                              \
      const int rb = c * 32 + w * 8;                                           \
      const size_t go = pbase + (size_t)(rb + srow) * 4096 + tb + scol;        \
      GLOAD_LDS16(Pt + go, &Ps[buf][rb * 64]);                                 \
      GLOAD_LDS16(kT + go, &Ks[buf][rb * 64]);                                 \
      GLOAD_LDS16(vT + go, &Vs[buf][rb * 64]);                                 \
    }                                                                          \
  }

  LG_STAGE(0, 0);
  asm volatile("s_waitcnt vmcnt(0)");
  __syncthreads();
  int cur = 0;
#pragma unroll
  for (int st = 0; st < 4; ++st) {
    if (st < 3) LG_STAGE(st + 1, cur ^ 1);
#pragma unroll
    for (int s = 0; s < 2; ++s) {
      short8 fp[4], fk[2], fv[2];
#pragma unroll
      for (int q = 0; q < 4; ++q)
        fp[q] = *(const short8*)&Ps[cur][(q * 16 + (l & 15)) * 64 + s * 32 + (l >> 4) * 8];
#pragma unroll
      for (int j = 0; j < 2; ++j)
        fk[j] = *(const short8*)&Ks[cur][(wc * 32 + j * 16 + (l & 15)) * 64 + s * 32 + (l >> 4) * 8];
#pragma unroll
      for (int i = 0; i < 2; ++i)
        fv[i] = *(const short8*)&Vs[cur][(wr * 32 + i * 16 + (l & 15)) * 64 + s * 32 + (l >> 4) * 8];
#pragma unroll
      for (int i = 0; i < 2; ++i)
#pragma unroll
        for (int j = 0; j < 2; ++j) {
          ak[i][j] = mfma16(fp[wr * 2 + i], fk[j], ak[i][j]);
          av[i][j] = mfma16(fv[i], fp[wc * 2 + j], av[i][j]);
        }
    }
    asm volatile("s_waitcnt vmcnt(0)");
    __syncthreads();
    cur ^= 1;
  }
#undef LG_STAGE
  float* pk = partials + ((size_t)(chunk * 64 + bh)) * 8192;
#pragma unroll
  for (int i = 0; i < 2; ++i)
#pragma unroll
    for (int j = 0; j < 2; ++j)
#pragma unroll
      for (int r = 0; r < 4; ++r) {
        const int rk = wr * 32 + i * 16 + (l >> 4) * 4 + r;   // m (k) / d (v)
        const int ck = wc * 32 + j * 16 + (l & 15);           // d (k) / m (v)
        pk[(size_t)rk * 64 + ck]        = ak[i][j][r];
        pk[4096 + (size_t)rk * 64 + ck] = av[i][j][r];
      }
}

// Sum 16 chunk-partials -> bf16 k_lat [bh][m][d] and v_latT [bh][d][m]
__global__ void latreduce(const float* __restrict__ partials,
                          __hip_bfloat16* __restrict__ k_lat,
                          __hip_bfloat16* __restrict__ v_latT) {
  const int i = blockIdx.x * 256 + threadIdx.x;   // 524288
  const int bh = i >> 13, off = i & 8191;
  float sm = 0.f;
#pragma unroll
  for (int c = 0; c < 16; ++c)
    sm += partials[((size_t)(c * 64 + bh)) * 8192 + off];
  if (off < 4096) k_lat[(size_t)bh * 4096 + off] = __float2bfloat16(sm);
  else            v_latT[(size_t)bh * 4096 + (off - 4096)] = __float2bfloat16(sm);
}

// ---------------------------------------------------------------- stage2 fused
__global__ __launch_bounds__(256)
void stage2_attn(const __hip_bfloat16* __restrict__ q,
                 const __hip_bfloat16* __restrict__ k_lat,
                 const __hip_bfloat16* __restrict__ v_latT,
                 __hip_bfloat16* __restrict__ attn) {
  __shared__ unsigned short Pl[4][16][64];
  const int bid = blockIdx.x;
  const int bh = bid >> 6, tt = (bid & 63) * 64;
  const int b = bh >> 4, h = bh & 15;
  const int tid = threadIdx.x, w = tid >> 6, l = tid & 63;
  const size_t qoff = ((size_t)(b * 4096 + tt + w * 16 + (l & 15)) * 16 + h) * 64;
  const short8 a0 = *(const short8*)&q[qoff + (l >> 4) * 8];
  const short8 a1 = *(const short8*)&q[qoff + 32 + (l >> 4) * 8];
  f32x4 att[4];
#pragma unroll
  for (int n = 0; n < 4; ++n) att[n] = ZERO4;
#pragma unroll
  for (int n = 0; n < 4; ++n) {
    const __hip_bfloat16* kl = &k_lat[((size_t)bh * 64 + n * 16 + (l & 15)) * 64];
    const short8 b0 = *(const short8*)&kl[(l >> 4) * 8];
    const short8 b1 = *(const short8*)&kl[32 + (l >> 4) * 8];
    att[n] = mfma16(a0, b0, att[n]);
    att[n] = mfma16(a1, b1, att[n]);
  }
  float p[4][4];
#pragma unroll
  for (int r = 0; r < 4; ++r) {
    const float v0 = att[0][r] * 0.125f, v1 = att[1][r] * 0.125f;
    const float v2 = att[2][r] * 0.125f, v3 = att[3][r] * 0.125f;
    float mxv = fmaxf(fmaxf(v0, v1), fmaxf(v2, v3));
#pragma unroll
    for (int o = 1; o < 16; o <<= 1) mxv = fmaxf(mxv, __shfl_xor(mxv, o, 64));
    const float e0 = __expf(v0 - mxv), e1 = __expf(v1 - mxv);
    const float e2 = __expf(v2 - mxv), e3 = __expf(v3 - mxv);
    float sum = e0 + e1 + e2 + e3;
#pragma unroll
    for (int o = 1; o < 16; o <<= 1) sum += __shfl_xor(sum, o, 64);
    const float inv = 1.f / sum;
    p[0][r] = e0 * inv; p[1][r] = e1 * inv; p[2][r] = e2 * inv; p[3][r] = e3 * inv;
  }
#pragma unroll
  for (int n = 0; n < 4; ++n)
#pragma unroll
    for (int r = 0; r < 4; ++r) {
      const int row = 4 * (l >> 4) + r;
      const int col = n * 16 + (l & 15);
      Pl[w][row][col ^ ((row & 7) << 3)] = f2bf(p[n][r]);
    }
  __syncthreads();
  const int arow = l & 15;
  const short8 pa0 = *(const short8*)&Pl[w][arow][(((l >> 4) + 0) ^ (arow & 7)) * 8];
  const short8 pa1 = *(const short8*)&Pl[w][arow][(((l >> 4) + 4) ^ (arow & 7)) * 8];
  f32x4 ov[4];
#pragma unroll
  for (int n = 0; n < 4; ++n) ov[n] = ZERO4;
#pragma unroll
  for (int n = 0; n < 4; ++n) {
    const __hip_bfloat16* vt = &v_latT[((size_t)bh * 64 + n * 16 + (l & 15)) * 64];
    const short8 b0 = *(const short8*)&vt[(l >> 4) * 8];
    const short8 b1 = *(const short8*)&vt[32 + (l >> 4) * 8];
    ov[n] = mfma16(pa0, b0, ov[n]);
    ov[n] = mfma16(pa1, b1, ov[n]);
  }
#pragma unroll
  for (int n = 0; n < 4; ++n) {
    const int d = n * 16 + (l & 15);
#pragma unroll
    for (int r = 0; r < 4; ++r) {
      const int trow = tt + w * 16 + 4 * (l >> 4) + r;
      attn[((size_t)(b * 4096 + trow) * 16 + h) * 64 + d] = __float2bfloat16(ov[n][r]);
    }
  }
}

// ---------------------------------------------------------------- launch
extern "C" void kernel_launch(void* const* d_in, const int* in_sizes, int n_in,
                              void* d_out, int out_size, void* d_ws, size_t ws_size,
                              hipStream_t stream) {
  const float* x      = (const float*)d_in[0];
  const float* Wq     = (const float*)d_in[1];
  const float* Wk     = (const float*)d_in[2];
  const float* Wv     = (const float*)d_in[3];
  const float* Wo     = (const float*)d_in[4];
  const float* latent = (const float*)d_in[5];
  const float* cosT   = (const float*)d_in[6];
  const float* sinT   = (const float*)d_in[7];
  const int*   mask   = (const int*)d_in[8];

  char* ws = (char*)d_ws;
  __hip_bfloat16* xb = (__hip_bfloat16*)ws;                        // 33.5MB (reused as Pt)
  __hip_bfloat16* Wb = (__hip_bfloat16*)(ws + 33554432);           // 8.4MB
  __hip_bfloat16* qb = (__hip_bfloat16*)(ws + 41943040);           // 33.5MB (reused as attn)
  __hip_bfloat16* kb = (__hip_bfloat16*)(ws + 75497472);           // 33.5MB (reused as partials)
  __hip_bfloat16* kT = (__hip_bfloat16*)(ws + 109051904);          // 33.5MB [bh*64+d][t]
  __hip_bfloat16* vT = (__hip_bfloat16*)(ws + 142606336);          // 33.5MB
  char* tail = ws + 176160768;
  float* pmax = (float*)tail;                       // 32768 f
  float* psum = pmax + 32768;
  float* cmax = psum + 32768;                       // 4096 f
  float* cinv = cmax + 4096;
  __hip_bfloat16* k_lat  = (__hip_bfloat16*)(cinv + 4096);   // 262144 bf16
  __hip_bfloat16* v_latT = k_lat + 262144;

  __hip_bfloat16* Pt   = xb;                // xb dead after projection GEMMs
  __hip_bfloat16* attn = qb;                // qb dead after stage2 (in-place ok: same layout)
  float* partials = (float*)kb;             // kb dead after stage1_pvals; 16*64*8192*4B = 33.5MB

  cvt_bf16<<<16384, 256, 0, stream>>>(x, xb, 16777216);
  cvt_bf16<<<1024, 256, 0, stream>>>(Wq, Wb + 0 * 1048576, 1048576);
  cvt_bf16<<<1024, 256, 0, stream>>>(Wk, Wb + 1 * 1048576, 1048576);
  cvt_bf16<<<1024, 256, 0, stream>>>(Wv, Wb + 2 * 1048576, 1048576);
  cvt_bf16<<<1024, 256, 0, stream>>>(Wo, Wb + 3 * 1048576, 1048576);

  dim3 gg(128, 8);
  gemm128<1, 1><<<gg, 256, 0, stream>>>(xb, Wb + 0 * 1048576, qb, nullptr, cosT, sinT, 16384, 1024, 1024);
  gemm128<2, 1><<<gg, 256, 0, stream>>>(xb, Wb + 1 * 1048576, kb, kT, cosT, sinT, 16384, 1024, 1024);
  gemm128<3, 0><<<gg, 256, 0, stream>>>(xb, Wb + 2 * 1048576, nullptr, vT, nullptr, nullptr, 16384, 1024, 1024);

  dim3 sg(64, 8);
  stage1_stats<<<sg, 256, 0, stream>>>(kb, latent, mask, pmax, psum);
  stage1_reduce<<<16, 256, 0, stream>>>(pmax, psum, cmax, cinv);
  stage1_pvals<<<1024, 256, 0, stream>>>(kb, latent, mask, cmax, cinv, Pt);

  dim3 lg(64, 16);
  latgemm3<<<lg, 256, 0, stream>>>(Pt, kT, vT, partials);
  latreduce<<<2048, 256, 0, stream>>>(partials, k_lat, v_latT);

  stage2_attn<<<4096, 256, 0, stream>>>(qb, k_lat, v_latT, attn);
  gemm128<0, 0><<<gg, 256, 0, stream>>>(attn, Wb + 3 * 1048576, d_out, nullptr, nullptr, nullptr, 16384, 1024, 1024);
}

// Round 4
// 471.170 us; speedup vs baseline: 1.4213x; 1.4213x over previous
//
#include <hip/hip_runtime.h>
#include <hip/hip_bf16.h>
#include <stdint.h>

// MLAAttention on MI355X (gfx950).
// B=4 T=4096 D=1024 H=16 M=64 Dh=64. All inputs f32 (mask int32), output f32.
// R4: latgemm4 = direct-from-global register-fragment MFMA reduction.
//     No LDS, no barriers, no global_load_lds: pure streaming (each Pt/kT/vT
//     byte read once, no reuse -> staging structure was pure overhead; R3
//     showed 383 GB/s latency-bound at 0.7% MfmaUtil).

#define DEV static __device__ __forceinline__

using short8 = __attribute__((ext_vector_type(8))) short;
using f32x4  = __attribute__((ext_vector_type(4))) float;

#define ZERO4 (f32x4){0.f, 0.f, 0.f, 0.f}

DEV float bf2f(unsigned short u) {
  union { unsigned int i; float f; } c; c.i = ((unsigned int)u) << 16; return c.f;
}
DEV unsigned short f2bf(float f) {
  __hip_bfloat16 h = __float2bfloat16(f);
  unsigned short u; __builtin_memcpy(&u, &h, 2); return u;
}
DEV f32x4 mfma16(short8 a, short8 b, f32x4 c) {
  return __builtin_amdgcn_mfma_f32_16x16x32_bf16(a, b, c, 0, 0, 0);
}
#define GLOAD_LDS16(G, L) __builtin_amdgcn_global_load_lds( \
    (const __attribute__((address_space(1))) void*)(G),     \
    (__attribute__((address_space(3))) void*)(L), 16, 0, 0)

// ---------------------------------------------------------------- convert
__global__ void cvt_bf16(const float* __restrict__ src,
                         __hip_bfloat16* __restrict__ dst, int n) {
  int i = (blockIdx.x * blockDim.x + threadIdx.x) * 4;
  if (i >= n) return;
  const float4 v = *(const float4*)(src + i);
  ushort4 o;
  o.x = f2bf(v.x); o.y = f2bf(v.y); o.z = f2bf(v.z); o.w = f2bf(v.w);
  *(ushort4*)(dst + i) = o;
}

// ---------------------------------------------------------------- GEMM 128x128
// C[M,N] = A[M,K] @ Bt[N,K]^T, bf16 in, f32 acc. m97 structure.
// MODE: 0 = f32 normal; 1 = bf16 normal; 2 = bf16 normal + bf16 transposed;
//       3 = bf16 transposed only.
// ROPE: apply rotary (pairs along n; t = m&4095, d = n&63) to acc before stores.
// Transposed layout: Ct[((m>>12)*16 + (n>>6))*64 + (n&63)][t = m&4095]  (bf16)
template<int MODE, int ROPE>
__global__ __launch_bounds__(256)
void gemm128(const __hip_bfloat16* __restrict__ A,
             const __hip_bfloat16* __restrict__ Bt,
             void* __restrict__ Cout, __hip_bfloat16* __restrict__ Ct,
             const float* __restrict__ cosT, const float* __restrict__ sinT,
             int M, int N, int K) {
  __shared__ __hip_bfloat16 As[128 * 64];
  __shared__ __hip_bfloat16 Bs[128 * 64];
  const int tid = threadIdx.x;
  const int w = tid >> 6, l = tid & 63;
  const int rowA0 = blockIdx.x * 128;
  const int colB0 = blockIdx.y * 128;
  const int srow = w * 8 + (l >> 3);
  const int skk  = (l & 7) * 8;
  const __hip_bfloat16* Ab = A  + (size_t)(rowA0 + srow) * K + skk;
  const __hip_bfloat16* Bb = Bt + (size_t)(colB0 + srow) * K + skk;
  f32x4 acc[4][4];
#pragma unroll
  for (int i = 0; i < 4; ++i)
#pragma unroll
    for (int j = 0; j < 4; ++j) acc[i][j] = ZERO4;
  const int wr = (w >> 1) * 64, wc = (w & 1) * 64;
  for (int k0 = 0; k0 < K; k0 += 64) {
    __syncthreads();
#pragma unroll
    for (int i = 0; i < 4; ++i) {
      GLOAD_LDS16(Ab + (size_t)(i * 32) * K + k0, &As[i * 2048 + w * 512]);
      GLOAD_LDS16(Bb + (size_t)(i * 32) * K + k0, &Bs[i * 2048 + w * 512]);
    }
    __syncthreads();
#pragma unroll
    for (int s = 0; s < 2; ++s) {
      short8 fa[4], fb[4];
#pragma unroll
      for (int i = 0; i < 4; ++i)
        fa[i] = *(const short8*)&As[(wr + i * 16 + (l & 15)) * 64 + s * 32 + (l >> 4) * 8];
#pragma unroll
      for (int j = 0; j < 4; ++j)
        fb[j] = *(const short8*)&Bs[(wc + j * 16 + (l & 15)) * 64 + s * 32 + (l >> 4) * 8];
#pragma unroll
      for (int i = 0; i < 4; ++i)
#pragma unroll
        for (int j = 0; j < 4; ++j)
          acc[i][j] = mfma16(fa[i], fb[j], acc[i][j]);
    }
  }
  const int r0 = rowA0 + wr + (l >> 4) * 4;   // global row (m) base, +i*16+r
  const int c0 = colB0 + wc + (l & 15);       // global col (n), +j*16
  if (ROPE) {
#pragma unroll
    for (int i = 0; i < 4; ++i)
#pragma unroll
      for (int j = 0; j < 4; ++j)
#pragma unroll
        for (int r = 0; r < 4; ++r) {
          const int m = r0 + i * 16 + r;
          const int n = c0 + j * 16;
          const int t = m & 4095, d = n & 63;
          const float c = cosT[t * 64 + d];
          const float s = sinT[t * 64 + d];
          const float v = acc[i][j][r];
          const float other = __shfl_xor(v, 1, 64);
          acc[i][j][r] = v * c + ((n & 1) ? other : -other) * s;
        }
  }
  if (MODE <= 2) {
#pragma unroll
    for (int i = 0; i < 4; ++i)
#pragma unroll
      for (int j = 0; j < 4; ++j)
#pragma unroll
        for (int r = 0; r < 4; ++r) {
          const size_t idx = (size_t)(r0 + i * 16 + r) * N + (c0 + j * 16);
          if (MODE == 0) ((float*)Cout)[idx] = acc[i][j][r];
          else ((__hip_bfloat16*)Cout)[idx] = __float2bfloat16(acc[i][j][r]);
        }
  }
  if (MODE >= 2) {
#pragma unroll
    for (int i = 0; i < 4; ++i)
#pragma unroll
      for (int j = 0; j < 4; ++j) {
        const int m0 = r0 + i * 16;           // 4 contiguous t per lane
        const int n  = c0 + j * 16;
        const size_t row = (size_t)(((m0 >> 12) * 16 + (n >> 6)) * 64 + (n & 63));
        ushort4 pk;
        pk.x = f2bf(acc[i][j][0]); pk.y = f2bf(acc[i][j][1]);
        pk.z = f2bf(acc[i][j][2]); pk.w = f2bf(acc[i][j][3]);
        *(ushort4*)&Ct[row * 4096 + (m0 & 4095)] = pk;
      }
  }
}

// ---------------------------------------------------------------- stage1 stats
__global__ __launch_bounds__(256)
void stage1_stats(const __hip_bfloat16* __restrict__ kmat,  // [B,T,H,64] (roped)
                  const float* __restrict__ latent,          // [H,64,64]
                  const int* __restrict__ mask,              // [B*T]
                  float* __restrict__ pmax, float* __restrict__ psum) {
  __shared__ __hip_bfloat16 kt[64][64];
  __shared__ float rmx[256], rsm[256];
  const int bh = blockIdx.x, chunk = blockIdx.y;
  const int b = bh >> 4, h = bh & 15;
  const int tid = threadIdx.x, m = tid & 63, g = tid >> 6;
  float latr[64];
#pragma unroll
  for (int d4 = 0; d4 < 16; ++d4) {
    const float4 v = *(const float4*)&latent[((size_t)(h * 64 + m)) * 64 + d4 * 4];
    latr[d4 * 4 + 0] = v.x; latr[d4 * 4 + 1] = v.y;
    latr[d4 * 4 + 2] = v.z; latr[d4 * 4 + 3] = v.w;
  }
  float mx = -3.0e38f, sm = 0.f;
  const int tbase = chunk * 512;
  for (int tt = 0; tt < 512; tt += 64) {
    __syncthreads();
    for (int i = tid; i < 512; i += 256) {
      const int r = i >> 3, o = (i & 7) * 8;
      *(uint4*)&kt[r][o] =
          *(const uint4*)&kmat[((size_t)(b * 4096 + tbase + tt + r) * 16 + h) * 64 + o];
    }
    __syncthreads();
    for (int tl = 0; tl < 16; ++tl) {
      const int t = g * 16 + tl;
      float dot = 0.f;
#pragma unroll
      for (int d8 = 0; d8 < 8; ++d8) {
        const short8 kv = *(const short8*)&kt[t][d8 * 8];
#pragma unroll
        for (int jj = 0; jj < 8; ++jj)
          dot += bf2f((unsigned short)kv[jj]) * latr[d8 * 8 + jj];
      }
      dot *= 0.125f;
      if (mask[b * 4096 + tbase + tt + t] != 0) {
        const float nmx = fmaxf(mx, dot);
        sm = sm * __expf(mx - nmx) + __expf(dot - nmx);
        mx = nmx;
      }
    }
  }
  rmx[tid] = mx; rsm[tid] = sm;
  __syncthreads();
  if (g == 0) {
#pragma unroll
    for (int gg = 1; gg < 4; ++gg) {
      const float omx = rmx[gg * 64 + m], osm = rsm[gg * 64 + m];
      const float nmx = fmaxf(mx, omx);
      sm = sm * __expf(mx - nmx) + osm * __expf(omx - nmx);
      mx = nmx;
    }
    pmax[((size_t)bh * 8 + chunk) * 64 + m] = mx;
    psum[((size_t)bh * 8 + chunk) * 64 + m] = sm;
  }
}

__global__ void stage1_reduce(const float* __restrict__ pmax,
                              const float* __restrict__ psum,
                              float* __restrict__ cmax, float* __restrict__ cinv) {
  const int i = blockIdx.x * 256 + threadIdx.x;
  if (i >= 4096) return;
  const int bh = i >> 6, m = i & 63;
  float mx = -3.0e38f;
#pragma unroll
  for (int c = 0; c < 8; ++c)
    mx = fmaxf(mx, pmax[((size_t)bh * 8 + c) * 64 + m]);
  float sm = 0.f;
#pragma unroll
  for (int c = 0; c < 8; ++c)
    sm += psum[((size_t)bh * 8 + c) * 64 + m] *
          __expf(pmax[((size_t)bh * 8 + c) * 64 + m] - mx);
  cmax[i] = mx;
  cinv[i] = 1.f / sm;
}

// P^T materialization: Pt[bh, m, t] bf16 (coalesced over t = lane)
__global__ __launch_bounds__(256)
void stage1_pvals(const __hip_bfloat16* __restrict__ kmat,
                  const float* __restrict__ latent,
                  const int* __restrict__ mask,
                  const float* __restrict__ cmax, const float* __restrict__ cinv,
                  __hip_bfloat16* __restrict__ Pt) {
  const int bh = blockIdx.x >> 4;
  const int t = (blockIdx.x & 15) * 256 + threadIdx.x;
  const int b = bh >> 4, h = bh & 15;
  float kr[64];
  {
    const __hip_bfloat16* kp = &kmat[((size_t)(b * 4096 + t) * 16 + h) * 64];
#pragma unroll
    for (int d8 = 0; d8 < 8; ++d8) {
      const short8 kv = *(const short8*)&kp[d8 * 8];
#pragma unroll
      for (int jj = 0; jj < 8; ++jj) kr[d8 * 8 + jj] = bf2f((unsigned short)kv[jj]);
    }
  }
  const bool live = (mask[b * 4096 + t] != 0);
  for (int m = 0; m < 64; ++m) {
    const float* lp = &latent[((size_t)h * 64 + m) * 64];
    float dot = 0.f;
#pragma unroll
    for (int dd = 0; dd < 64; ++dd) dot += kr[dd] * lp[dd];
    dot *= 0.125f;
    const float p = live ? __expf(dot - cmax[bh * 64 + m]) * cinv[bh * 64 + m] : 0.f;
    Pt[((size_t)bh * 64 + m) * 4096 + t] = __float2bfloat16(p);
  }
}

// ---------------------------------------------------------------- latent GEMM v4
// Pure register-fragment reduction, no LDS/barriers. Wave = (bh, 256-t slice).
// k_lat_part[m,d] = sum_t Pt[m,t]*kT[d,t]; v_latT_part[d,m] = sum_t vT[d,t]*Pt[m,t].
// grid (64 bh, 4); 4 waves/block, wave w -> slice blockIdx.y*4+w (16 slices).
__global__ __launch_bounds__(256)
void latgemm4(const __hip_bfloat16* __restrict__ Pt,
              const __hip_bfloat16* __restrict__ kT,
              const __hip_bfloat16* __restrict__ vT,
              float* __restrict__ partials) {   // [slice][bh][8192]
  const int bh = blockIdx.x;
  const int tid = threadIdx.x, w = tid >> 6, l = tid & 63;
  const int slice = blockIdx.y * 4 + w;
  const int lr = l & 15;            // frag row
  const int lk = (l >> 4) * 8;      // frag k-offset
  const size_t base = (size_t)bh * 64 * 4096;
  f32x4 ak[4][4], av[4][4];
#pragma unroll
  for (int i = 0; i < 4; ++i)
#pragma unroll
    for (int j = 0; j < 4; ++j) { ak[i][j] = ZERO4; av[i][j] = ZERO4; }
  for (int ks = 0; ks < 8; ++ks) {
    const int t = slice * 256 + ks * 32 + lk;
    short8 fp[4], fk[4], fv[4];
#pragma unroll
    for (int i = 0; i < 4; ++i) {
      const size_t ro = base + (size_t)(i * 16 + lr) * 4096 + t;
      fp[i] = *(const short8*)&Pt[ro];
      fk[i] = *(const short8*)&kT[ro];
      fv[i] = *(const short8*)&vT[ro];
    }
#pragma unroll
    for (int i = 0; i < 4; ++i)
#pragma unroll
      for (int j = 0; j < 4; ++j) {
        ak[i][j] = mfma16(fp[i], fk[j], ak[i][j]);   // C[m][d]
        av[i][j] = mfma16(fv[i], fp[j], av[i][j]);   // C[d][m]
      }
  }
  float* pk = partials + ((size_t)(slice * 64 + bh)) * 8192;
#pragma unroll
  for (int i = 0; i < 4; ++i)
#pragma unroll
    for (int j = 0; j < 4; ++j)
#pragma unroll
      for (int r = 0; r < 4; ++r) {
        const int row = i * 16 + 4 * (l >> 4) + r;
        const int col = j * 16 + lr;
        pk[(size_t)row * 64 + col]        = ak[i][j][r];
        pk[4096 + (size_t)row * 64 + col] = av[i][j][r];
      }
}

// Sum 16 slice-partials -> bf16 k_lat [bh][m][d] and v_latT [bh][d][m]
__global__ void latreduce(const float* __restrict__ partials,
                          __hip_bfloat16* __restrict__ k_lat,
                          __hip_bfloat16* __restrict__ v_latT) {
  const int i = blockIdx.x * 256 + threadIdx.x;   // 524288
  const int bh = i >> 13, off = i & 8191;
  float sm = 0.f;
#pragma unroll
  for (int c = 0; c < 16; ++c)
    sm += partials[((size_t)(c * 64 + bh)) * 8192 + off];
  if (off < 4096) k_lat[(size_t)bh * 4096 + off] = __float2bfloat16(sm);
  else            v_latT[(size_t)bh * 4096 + (off - 4096)] = __float2bfloat16(sm);
}

// ---------------------------------------------------------------- stage2 fused
__global__ __launch_bounds__(256)
void stage2_attn(const __hip_bfloat16* __restrict__ q,
                 const __hip_bfloat16* __restrict__ k_lat,
                 const __hip_bfloat16* __restrict__ v_latT,
                 __hip_bfloat16* __restrict__ attn) {
  __shared__ unsigned short Pl[4][16][64];
  const int bid = blockIdx.x;
  const int bh = bid >> 6, tt = (bid & 63) * 64;
  const int b = bh >> 4, h = bh & 15;
  const int tid = threadIdx.x, w = tid >> 6, l = tid & 63;
  const size_t qoff = ((size_t)(b * 4096 + tt + w * 16 + (l & 15)) * 16 + h) * 64;
  const short8 a0 = *(const short8*)&q[qoff + (l >> 4) * 8];
  const short8 a1 = *(const short8*)&q[qoff + 32 + (l >> 4) * 8];
  f32x4 att[4];
#pragma unroll
  for (int n = 0; n < 4; ++n) att[n] = ZERO4;
#pragma unroll
  for (int n = 0; n < 4; ++n) {
    const __hip_bfloat16* kl = &k_lat[((size_t)bh * 64 + n * 16 + (l & 15)) * 64];
    const short8 b0 = *(const short8*)&kl[(l >> 4) * 8];
    const short8 b1 = *(const short8*)&kl[32 + (l >> 4) * 8];
    att[n] = mfma16(a0, b0, att[n]);
    att[n] = mfma16(a1, b1, att[n]);
  }
  float p[4][4];
#pragma unroll
  for (int r = 0; r < 4; ++r) {
    const float v0 = att[0][r] * 0.125f, v1 = att[1][r] * 0.125f;
    const float v2 = att[2][r] * 0.125f, v3 = att[3][r] * 0.125f;
    float mxv = fmaxf(fmaxf(v0, v1), fmaxf(v2, v3));
#pragma unroll
    for (int o = 1; o < 16; o <<= 1) mxv = fmaxf(mxv, __shfl_xor(mxv, o, 64));
    const float e0 = __expf(v0 - mxv), e1 = __expf(v1 - mxv);
    const float e2 = __expf(v2 - mxv), e3 = __expf(v3 - mxv);
    float sum = e0 + e1 + e2 + e3;
#pragma unroll
    for (int o = 1; o < 16; o <<= 1) sum += __shfl_xor(sum, o, 64);
    const float inv = 1.f / sum;
    p[0][r] = e0 * inv; p[1][r] = e1 * inv; p[2][r] = e2 * inv; p[3][r] = e3 * inv;
  }
#pragma unroll
  for (int n = 0; n < 4; ++n)
#pragma unroll
    for (int r = 0; r < 4; ++r) {
      const int row = 4 * (l >> 4) + r;
      const int col = n * 16 + (l & 15);
      Pl[w][row][col ^ ((row & 7) << 3)] = f2bf(p[n][r]);
    }
  __syncthreads();
  const int arow = l & 15;
  const short8 pa0 = *(const short8*)&Pl[w][arow][(((l >> 4) + 0) ^ (arow & 7)) * 8];
  const short8 pa1 = *(const short8*)&Pl[w][arow][(((l >> 4) + 4) ^ (arow & 7)) * 8];
  f32x4 ov[4];
#pragma unroll
  for (int n = 0; n < 4; ++n) ov[n] = ZERO4;
#pragma unroll
  for (int n = 0; n < 4; ++n) {
    const __hip_bfloat16* vt = &v_latT[((size_t)bh * 64 + n * 16 + (l & 15)) * 64];
    const short8 b0 = *(const short8*)&vt[(l >> 4) * 8];
    const short8 b1 = *(const short8*)&vt[32 + (l >> 4) * 8];
    ov[n] = mfma16(pa0, b0, ov[n]);
    ov[n] = mfma16(pa1, b1, ov[n]);
  }
#pragma unroll
  for (int n = 0; n < 4; ++n) {
    const int d = n * 16 + (l & 15);
#pragma unroll
    for (int r = 0; r < 4; ++r) {
      const int trow = tt + w * 16 + 4 * (l >> 4) + r;
      attn[((size_t)(b * 4096 + trow) * 16 + h) * 64 + d] = __float2bfloat16(ov[n][r]);
    }
  }
}

// ---------------------------------------------------------------- launch
extern "C" void kernel_launch(void* const* d_in, const int* in_sizes, int n_in,
                              void* d_out, int out_size, void* d_ws, size_t ws_size,
                              hipStream_t stream) {
  const float* x      = (const float*)d_in[0];
  const float* Wq     = (const float*)d_in[1];
  const float* Wk     = (const float*)d_in[2];
  const float* Wv     = (const float*)d_in[3];
  const float* Wo     = (const float*)d_in[4];
  const float* latent = (const float*)d_in[5];
  const float* cosT   = (const float*)d_in[6];
  const float* sinT   = (const float*)d_in[7];
  const int*   mask   = (const int*)d_in[8];

  char* ws = (char*)d_ws;
  __hip_bfloat16* xb = (__hip_bfloat16*)ws;                        // 33.5MB (reused as Pt)
  __hip_bfloat16* Wb = (__hip_bfloat16*)(ws + 33554432);           // 8.4MB
  __hip_bfloat16* qb = (__hip_bfloat16*)(ws + 41943040);           // 33.5MB (reused as attn)
  __hip_bfloat16* kb = (__hip_bfloat16*)(ws + 75497472);           // 33.5MB (reused as partials)
  __hip_bfloat16* kT = (__hip_bfloat16*)(ws + 109051904);          // 33.5MB [bh*64+d][t]
  __hip_bfloat16* vT = (__hip_bfloat16*)(ws + 142606336);          // 33.5MB
  char* tail = ws + 176160768;
  float* pmax = (float*)tail;                       // 32768 f
  float* psum = pmax + 32768;
  float* cmax = psum + 32768;                       // 4096 f
  float* cinv = cmax + 4096;
  __hip_bfloat16* k_lat  = (__hip_bfloat16*)(cinv + 4096);   // 262144 bf16
  __hip_bfloat16* v_latT = k_lat + 262144;

  __hip_bfloat16* Pt   = xb;                // xb dead after projection GEMMs
  __hip_bfloat16* attn = qb;                // qb dead after stage2 (in-place ok)
  float* partials = (float*)kb;             // kb dead after stage1_pvals

  cvt_bf16<<<16384, 256, 0, stream>>>(x, xb, 16777216);
  cvt_bf16<<<1024, 256, 0, stream>>>(Wq, Wb + 0 * 1048576, 1048576);
  cvt_bf16<<<1024, 256, 0, stream>>>(Wk, Wb + 1 * 1048576, 1048576);
  cvt_bf16<<<1024, 256, 0, stream>>>(Wv, Wb + 2 * 1048576, 1048576);
  cvt_bf16<<<1024, 256, 0, stream>>>(Wo, Wb + 3 * 1048576, 1048576);

  dim3 gg(128, 8);
  gemm128<1, 1><<<gg, 256, 0, stream>>>(xb, Wb + 0 * 1048576, qb, nullptr, cosT, sinT, 16384, 1024, 1024);
  gemm128<2, 1><<<gg, 256, 0, stream>>>(xb, Wb + 1 * 1048576, kb, kT, cosT, sinT, 16384, 1024, 1024);
  gemm128<3, 0><<<gg, 256, 0, stream>>>(xb, Wb + 2 * 1048576, nullptr, vT, nullptr, nullptr, 16384, 1024, 1024);

  dim3 sg(64, 8);
  stage1_stats<<<sg, 256, 0, stream>>>(kb, latent, mask, pmax, psum);
  stage1_reduce<<<16, 256, 0, stream>>>(pmax, psum, cmax, cinv);
  stage1_pvals<<<1024, 256, 0, stream>>>(kb, latent, mask, cmax, cinv, Pt);

  dim3 lg(64, 4);
  latgemm4<<<lg, 256, 0, stream>>>(Pt, kT, vT, partials);
  latreduce<<<2048, 256, 0, stream>>>(partials, k_lat, v_latT);

  stage2_attn<<<4096, 256, 0, stream>>>(qb, k_lat, v_latT, attn);
  gemm128<0, 0><<<gg, 256, 0, stream>>>(attn, Wb + 3 * 1048576, d_out, nullptr, nullptr, nullptr, 16384, 1024, 1024);
}

// Round 5
// 390.758 us; speedup vs baseline: 1.7138x; 1.2058x over previous
//
#include <hip/hip_runtime.h>
#include <hip/hip_bf16.h>
#include <stdint.h>

// MLAAttention on MI355X (gfx950).
// B=4 T=4096 D=1024 H=16 M=64 Dh=64. All inputs f32 (mask int32), output f32.
// R5: stage1 logits via MFMA (computed ONCE, in Pt layout, fused online stats);
//     pvals becomes a pure elementwise exp pass (in-place). Replaces the two
//     scalar-VALU dot kernels (stage1_stats 84us @ 78% VALU / 0% MFMA).

#define DEV static __device__ __forceinline__

using short8 = __attribute__((ext_vector_type(8))) short;
using f32x4  = __attribute__((ext_vector_type(4))) float;

#define ZERO4 (f32x4){0.f, 0.f, 0.f, 0.f}

DEV float bf2f(unsigned short u) {
  union { unsigned int i; float f; } c; c.i = ((unsigned int)u) << 16; return c.f;
}
DEV unsigned short f2bf(float f) {
  __hip_bfloat16 h = __float2bfloat16(f);
  unsigned short u; __builtin_memcpy(&u, &h, 2); return u;
}
DEV f32x4 mfma16(short8 a, short8 b, f32x4 c) {
  return __builtin_amdgcn_mfma_f32_16x16x32_bf16(a, b, c, 0, 0, 0);
}
#define GLOAD_LDS16(G, L) __builtin_amdgcn_global_load_lds( \
    (const __attribute__((address_space(1))) void*)(G),     \
    (__attribute__((address_space(3))) void*)(L), 16, 0, 0)

// ---------------------------------------------------------------- convert
__global__ void cvt_bf16(const float* __restrict__ src,
                         __hip_bfloat16* __restrict__ dst, int n) {
  int i = (blockIdx.x * blockDim.x + threadIdx.x) * 4;
  if (i >= n) return;
  const float4 v = *(const float4*)(src + i);
  ushort4 o;
  o.x = f2bf(v.x); o.y = f2bf(v.y); o.z = f2bf(v.z); o.w = f2bf(v.w);
  *(ushort4*)(dst + i) = o;
}

// ---------------------------------------------------------------- GEMM 128x128
// C[M,N] = A[M,K] @ Bt[N,K]^T, bf16 in, f32 acc. m97 structure.
// MODE: 0 = f32 normal; 1 = bf16 normal; 2 = bf16 normal + bf16 transposed;
//       3 = bf16 transposed only.
// ROPE: apply rotary (pairs along n; t = m&4095, d = n&63) to acc before stores.
// Transposed layout: Ct[((m>>12)*16 + (n>>6))*64 + (n&63)][t = m&4095]  (bf16)
template<int MODE, int ROPE>
__global__ __launch_bounds__(256)
void gemm128(const __hip_bfloat16* __restrict__ A,
             const __hip_bfloat16* __restrict__ Bt,
             void* __restrict__ Cout, __hip_bfloat16* __restrict__ Ct,
             const float* __restrict__ cosT, const float* __restrict__ sinT,
             int M, int N, int K) {
  __shared__ __hip_bfloat16 As[128 * 64];
  __shared__ __hip_bfloat16 Bs[128 * 64];
  const int tid = threadIdx.x;
  const int w = tid >> 6, l = tid & 63;
  const int rowA0 = blockIdx.x * 128;
  const int colB0 = blockIdx.y * 128;
  const int srow = w * 8 + (l >> 3);
  const int skk  = (l & 7) * 8;
  const __hip_bfloat16* Ab = A  + (size_t)(rowA0 + srow) * K + skk;
  const __hip_bfloat16* Bb = Bt + (size_t)(colB0 + srow) * K + skk;
  f32x4 acc[4][4];
#pragma unroll
  for (int i = 0; i < 4; ++i)
#pragma unroll
    for (int j = 0; j < 4; ++j) acc[i][j] = ZERO4;
  const int wr = (w >> 1) * 64, wc = (w & 1) * 64;
  for (int k0 = 0; k0 < K; k0 += 64) {
    __syncthreads();
#pragma unroll
    for (int i = 0; i < 4; ++i) {
      GLOAD_LDS16(Ab + (size_t)(i * 32) * K + k0, &As[i * 2048 + w * 512]);
      GLOAD_LDS16(Bb + (size_t)(i * 32) * K + k0, &Bs[i * 2048 + w * 512]);
    }
    __syncthreads();
#pragma unroll
    for (int s = 0; s < 2; ++s) {
      short8 fa[4], fb[4];
#pragma unroll
      for (int i = 0; i < 4; ++i)
        fa[i] = *(const short8*)&As[(wr + i * 16 + (l & 15)) * 64 + s * 32 + (l >> 4) * 8];
#pragma unroll
      for (int j = 0; j < 4; ++j)
        fb[j] = *(const short8*)&Bs[(wc + j * 16 + (l & 15)) * 64 + s * 32 + (l >> 4) * 8];
#pragma unroll
      for (int i = 0; i < 4; ++i)
#pragma unroll
        for (int j = 0; j < 4; ++j)
          acc[i][j] = mfma16(fa[i], fb[j], acc[i][j]);
    }
  }
  const int r0 = rowA0 + wr + (l >> 4) * 4;   // global row (m) base, +i*16+r
  const int c0 = colB0 + wc + (l & 15);       // global col (n), +j*16
  if (ROPE) {
#pragma unroll
    for (int i = 0; i < 4; ++i)
#pragma unroll
      for (int j = 0; j < 4; ++j)
#pragma unroll
        for (int r = 0; r < 4; ++r) {
          const int m = r0 + i * 16 + r;
          const int n = c0 + j * 16;
          const int t = m & 4095, d = n & 63;
          const float c = cosT[t * 64 + d];
          const float s = sinT[t * 64 + d];
          const float v = acc[i][j][r];
          const float other = __shfl_xor(v, 1, 64);
          acc[i][j][r] = v * c + ((n & 1) ? other : -other) * s;
        }
  }
  if (MODE <= 2) {
#pragma unroll
    for (int i = 0; i < 4; ++i)
#pragma unroll
      for (int j = 0; j < 4; ++j)
#pragma unroll
        for (int r = 0; r < 4; ++r) {
          const size_t idx = (size_t)(r0 + i * 16 + r) * N + (c0 + j * 16);
          if (MODE == 0) ((float*)Cout)[idx] = acc[i][j][r];
          else ((__hip_bfloat16*)Cout)[idx] = __float2bfloat16(acc[i][j][r]);
        }
  }
  if (MODE >= 2) {
#pragma unroll
    for (int i = 0; i < 4; ++i)
#pragma unroll
      for (int j = 0; j < 4; ++j) {
        const int m0 = r0 + i * 16;           // 4 contiguous t per lane
        const int n  = c0 + j * 16;
        const size_t row = (size_t)(((m0 >> 12) * 16 + (n >> 6)) * 64 + (n & 63));
        ushort4 pk;
        pk.x = f2bf(acc[i][j][0]); pk.y = f2bf(acc[i][j][1]);
        pk.z = f2bf(acc[i][j][2]); pk.w = f2bf(acc[i][j][3]);
        *(ushort4*)&Ct[row * 4096 + (m0 & 4095)] = pk;
      }
  }
}

// ---------------------------------------------------------------- stage1 logits (MFMA)
// S[bh][m][t] = 0.125 * sum_d latent[h][m][d]*K[b][t][h][d]  (bf16 store; -inf if masked)
// Fused online per-m (max,sum) partials: pmax/psum[(bh*8+chunk)*4 + wave][m].
// grid (bh=64, chunk=8), 4 waves; wave w covers t in {chunk*512 + tile*64 + w*16 + lr}.
__global__ __launch_bounds__(256)
void stage1_logits(const __hip_bfloat16* __restrict__ kmat,  // [B,T,H,64] (roped)
                   const float* __restrict__ latent,          // [H,64,64] f32
                   const int* __restrict__ mask,               // [B*T]
                   __hip_bfloat16* __restrict__ S,             // [bh][64][4096]
                   float* __restrict__ pmax, float* __restrict__ psum) {
  const int bh = blockIdx.x, chunk = blockIdx.y;
  const int b = bh >> 4, h = bh & 15;
  const int tid = threadIdx.x, w = tid >> 6, l = tid & 63;
  const int lr = l & 15, lg = l >> 4;
  // A-frags: latent row m' = n*16+lr, k-offset s*32 + lg*8 (convert f32->bf16 once)
  short8 la[4][2];
#pragma unroll
  for (int n = 0; n < 4; ++n)
#pragma unroll
    for (int s = 0; s < 2; ++s) {
      const float* lp = &latent[((size_t)h * 64 + n * 16 + lr) * 64 + s * 32 + lg * 8];
      short8 f;
#pragma unroll
      for (int j = 0; j < 8; ++j) f[j] = (short)f2bf(lp[j]);
      la[n][s] = f;
    }
  float mx[16], sm[16];
#pragma unroll
  for (int i = 0; i < 16; ++i) { mx[i] = -3.0e38f; sm[i] = 0.f; }
  for (int tile = 0; tile < 8; ++tile) {
    const int t = chunk * 512 + tile * 64 + w * 16 + lr;
    const __hip_bfloat16* kp = &kmat[((size_t)(b * 4096 + t) * 16 + h) * 64 + lg * 8];
    const short8 kb0 = *(const short8*)kp;
    const short8 kb1 = *(const short8*)(kp + 32);
    const bool live = (mask[b * 4096 + t] != 0);
    f32x4 acc[4];
#pragma unroll
    for (int n = 0; n < 4; ++n) {
      acc[n] = ZERO4;
      acc[n] = mfma16(la[n][0], kb0, acc[n]);
      acc[n] = mfma16(la[n][1], kb1, acc[n]);
    }
#pragma unroll
    for (int n = 0; n < 4; ++n)
#pragma unroll
      for (int r = 0; r < 4; ++r) {
        const float v = acc[n][r] * 0.125f;
        const int m = n * 16 + lg * 4 + r;
        unsigned short sv = live ? f2bf(v) : (unsigned short)0xFF80;  // -inf
        ((unsigned short*)S)[((size_t)bh * 64 + m) * 4096 + t] = sv;
        if (live) {
          const int idx = n * 4 + r;
          const float nm = fmaxf(mx[idx], v);
          sm[idx] = sm[idx] * __expf(mx[idx] - nm) + __expf(v - nm);
          mx[idx] = nm;
        }
      }
  }
  // combine across the 16-lane t-group (xor 1,2,4,8)
#pragma unroll
  for (int o = 1; o < 16; o <<= 1)
#pragma unroll
    for (int i = 0; i < 16; ++i) {
      const float omx = __shfl_xor(mx[i], o, 64);
      const float osm = __shfl_xor(sm[i], o, 64);
      const float nm = fmaxf(mx[i], omx);
      sm[i] = sm[i] * __expf(mx[i] - nm) + osm * __expf(omx - nm);
      mx[i] = nm;
    }
  if (lr == 0) {
    const size_t pb = ((size_t)(bh * 8 + chunk) * 4 + w) * 64;
#pragma unroll
    for (int n = 0; n < 4; ++n)
#pragma unroll
      for (int r = 0; r < 4; ++r) {
        const int m = n * 16 + lg * 4 + r;
        pmax[pb + m] = mx[n * 4 + r];
        psum[pb + m] = sm[n * 4 + r];
      }
  }
}

// combine 32 partials per (bh,m)
__global__ void stage1_reduce(const float* __restrict__ pmax,
                              const float* __restrict__ psum,
                              float* __restrict__ cmax, float* __restrict__ cinv) {
  const int i = blockIdx.x * 256 + threadIdx.x;
  if (i >= 4096) return;
  const int bh = i >> 6, m = i & 63;
  float mx = -3.0e38f;
#pragma unroll
  for (int c = 0; c < 32; ++c)
    mx = fmaxf(mx, pmax[((size_t)bh * 32 + c) * 64 + m]);
  float sm = 0.f;
#pragma unroll
  for (int c = 0; c < 32; ++c)
    sm += psum[((size_t)bh * 32 + c) * 64 + m] *
          __expf(pmax[((size_t)bh * 32 + c) * 64 + m] - mx);
  cmax[i] = mx;
  cinv[i] = 1.f / sm;
}

// In-place: Pt[i] = exp(logit - cmax)*cinv. Masked logits are -inf -> exp = 0.
__global__ void stage1_pvals2(__hip_bfloat16* __restrict__ Pt,
                              const float* __restrict__ cmax,
                              const float* __restrict__ cinv) {
  const size_t i = ((size_t)blockIdx.x * 256 + threadIdx.x) * 8;  // 16,777,216 total
  const int bh = (int)(i >> 18);
  const int m  = (int)((i >> 12) & 63);
  const float cm = cmax[bh * 64 + m], ci = cinv[bh * 64 + m];
  short8 sv = *(short8*)&Pt[i];
  short8 ov;
#pragma unroll
  for (int j = 0; j < 8; ++j) {
    const float p = __expf(bf2f((unsigned short)sv[j]) - cm) * ci;
    ov[j] = (short)f2bf(p);
  }
  *(short8*)&Pt[i] = ov;
}

// ---------------------------------------------------------------- latent GEMM v4
// Pure register-fragment reduction, no LDS/barriers. Wave = (bh, 256-t slice).
// k_lat_part[m,d] = sum_t Pt[m,t]*kT[d,t]; v_latT_part[d,m] = sum_t vT[d,t]*Pt[m,t].
// grid (64 bh, 4); 4 waves/block, wave w -> slice blockIdx.y*4+w (16 slices).
__global__ __launch_bounds__(256)
void latgemm4(const __hip_bfloat16* __restrict__ Pt,
              const __hip_bfloat16* __restrict__ kT,
              const __hip_bfloat16* __restrict__ vT,
              float* __restrict__ partials) {   // [slice][bh][8192]
  const int bh = blockIdx.x;
  const int tid = threadIdx.x, w = tid >> 6, l = tid & 63;
  const int slice = blockIdx.y * 4 + w;
  const int lr = l & 15;            // frag row
  const int lk = (l >> 4) * 8;      // frag k-offset
  const size_t base = (size_t)bh * 64 * 4096;
  f32x4 ak[4][4], av[4][4];
#pragma unroll
  for (int i = 0; i < 4; ++i)
#pragma unroll
    for (int j = 0; j < 4; ++j) { ak[i][j] = ZERO4; av[i][j] = ZERO4; }
  for (int ks = 0; ks < 8; ++ks) {
    const int t = slice * 256 + ks * 32 + lk;
    short8 fp[4], fk[4], fv[4];
#pragma unroll
    for (int i = 0; i < 4; ++i) {
      const size_t ro = base + (size_t)(i * 16 + lr) * 4096 + t;
      fp[i] = *(const short8*)&Pt[ro];
      fk[i] = *(const short8*)&kT[ro];
      fv[i] = *(const short8*)&vT[ro];
    }
#pragma unroll
    for (int i = 0; i < 4; ++i)
#pragma unroll
      for (int j = 0; j < 4; ++j) {
        ak[i][j] = mfma16(fp[i], fk[j], ak[i][j]);   // C[m][d]
        av[i][j] = mfma16(fv[i], fp[j], av[i][j]);   // C[d][m]
      }
  }
  float* pk = partials + ((size_t)(slice * 64 + bh)) * 8192;
#pragma unroll
  for (int i = 0; i < 4; ++i)
#pragma unroll
    for (int j = 0; j < 4; ++j)
#pragma unroll
      for (int r = 0; r < 4; ++r) {
        const int row = i * 16 + 4 * (l >> 4) + r;
        const int col = j * 16 + lr;
        pk[(size_t)row * 64 + col]        = ak[i][j][r];
        pk[4096 + (size_t)row * 64 + col] = av[i][j][r];
      }
}

// Sum 16 slice-partials -> bf16 k_lat [bh][m][d] and v_latT [bh][d][m]
__global__ void latreduce(const float* __restrict__ partials,
                          __hip_bfloat16* __restrict__ k_lat,
                          __hip_bfloat16* __restrict__ v_latT) {
  const int i = blockIdx.x * 256 + threadIdx.x;   // 524288
  const int bh = i >> 13, off = i & 8191;
  float sm = 0.f;
#pragma unroll
  for (int c = 0; c < 16; ++c)
    sm += partials[((size_t)(c * 64 + bh)) * 8192 + off];
  if (off < 4096) k_lat[(size_t)bh * 4096 + off] = __float2bfloat16(sm);
  else            v_latT[(size_t)bh * 4096 + (off - 4096)] = __float2bfloat16(sm);
}

// ---------------------------------------------------------------- stage2 fused
__global__ __launch_bounds__(256)
void stage2_attn(const __hip_bfloat16* __restrict__ q,
                 const __hip_bfloat16* __restrict__ k_lat,
                 const __hip_bfloat16* __restrict__ v_latT,
                 __hip_bfloat16* __restrict__ attn) {
  __shared__ unsigned short Pl[4][16][64];
  const int bid = blockIdx.x;
  const int bh = bid >> 6, tt = (bid & 63) * 64;
  const int b = bh >> 4, h = bh & 15;
  const int tid = threadIdx.x, w = tid >> 6, l = tid & 63;
  const size_t qoff = ((size_t)(b * 4096 + tt + w * 16 + (l & 15)) * 16 + h) * 64;
  const short8 a0 = *(const short8*)&q[qoff + (l >> 4) * 8];
  const short8 a1 = *(const short8*)&q[qoff + 32 + (l >> 4) * 8];
  f32x4 att[4];
#pragma unroll
  for (int n = 0; n < 4; ++n) att[n] = ZERO4;
#pragma unroll
  for (int n = 0; n < 4; ++n) {
    const __hip_bfloat16* kl = &k_lat[((size_t)bh * 64 + n * 16 + (l & 15)) * 64];
    const short8 b0 = *(const short8*)&kl[(l >> 4) * 8];
    const short8 b1 = *(const short8*)&kl[32 + (l >> 4) * 8];
    att[n] = mfma16(a0, b0, att[n]);
    att[n] = mfma16(a1, b1, att[n]);
  }
  float p[4][4];
#pragma unroll
  for (int r = 0; r < 4; ++r) {
    const float v0 = att[0][r] * 0.125f, v1 = att[1][r] * 0.125f;
    const float v2 = att[2][r] * 0.125f, v3 = att[3][r] * 0.125f;
    float mxv = fmaxf(fmaxf(v0, v1), fmaxf(v2, v3));
#pragma unroll
    for (int o = 1; o < 16; o <<= 1) mxv = fmaxf(mxv, __shfl_xor(mxv, o, 64));
    const float e0 = __expf(v0 - mxv), e1 = __expf(v1 - mxv);
    const float e2 = __expf(v2 - mxv), e3 = __expf(v3 - mxv);
    float sum = e0 + e1 + e2 + e3;
#pragma unroll
    for (int o = 1; o < 16; o <<= 1) sum += __shfl_xor(sum, o, 64);
    const float inv = 1.f / sum;
    p[0][r] = e0 * inv; p[1][r] = e1 * inv; p[2][r] = e2 * inv; p[3][r] = e3 * inv;
  }
#pragma unroll
  for (int n = 0; n < 4; ++n)
#pragma unroll
    for (int r = 0; r < 4; ++r) {
      const int row = 4 * (l >> 4) + r;
      const int col = n * 16 + (l & 15);
      Pl[w][row][col ^ ((row & 7) << 3)] = f2bf(p[n][r]);
    }
  __syncthreads();
  const int arow = l & 15;
  const short8 pa0 = *(const short8*)&Pl[w][arow][(((l >> 4) + 0) ^ (arow & 7)) * 8];
  const short8 pa1 = *(const short8*)&Pl[w][arow][(((l >> 4) + 4) ^ (arow & 7)) * 8];
  f32x4 ov[4];
#pragma unroll
  for (int n = 0; n < 4; ++n) ov[n] = ZERO4;
#pragma unroll
  for (int n = 0; n < 4; ++n) {
    const __hip_bfloat16* vt = &v_latT[((size_t)bh * 64 + n * 16 + (l & 15)) * 64];
    const short8 b0 = *(const short8*)&vt[(l >> 4) * 8];
    const short8 b1 = *(const short8*)&vt[32 + (l >> 4) * 8];
    ov[n] = mfma16(pa0, b0, ov[n]);
    ov[n] = mfma16(pa1, b1, ov[n]);
  }
#pragma unroll
  for (int n = 0; n < 4; ++n) {
    const int d = n * 16 + (l & 15);
#pragma unroll
    for (int r = 0; r < 4; ++r) {
      const int trow = tt + w * 16 + 4 * (l >> 4) + r;
      attn[((size_t)(b * 4096 + trow) * 16 + h) * 64 + d] = __float2bfloat16(ov[n][r]);
    }
  }
}

// ---------------------------------------------------------------- launch
extern "C" void kernel_launch(void* const* d_in, const int* in_sizes, int n_in,
                              void* d_out, int out_size, void* d_ws, size_t ws_size,
                              hipStream_t stream) {
  const float* x      = (const float*)d_in[0];
  const float* Wq     = (const float*)d_in[1];
  const float* Wk     = (const float*)d_in[2];
  const float* Wv     = (const float*)d_in[3];
  const float* Wo     = (const float*)d_in[4];
  const float* latent = (const float*)d_in[5];
  const float* cosT   = (const float*)d_in[6];
  const float* sinT   = (const float*)d_in[7];
  const int*   mask   = (const int*)d_in[8];

  char* ws = (char*)d_ws;
  __hip_bfloat16* xb = (__hip_bfloat16*)ws;                        // 33.5MB (reused as Pt/S)
  __hip_bfloat16* Wb = (__hip_bfloat16*)(ws + 33554432);           // 8.4MB
  __hip_bfloat16* qb = (__hip_bfloat16*)(ws + 41943040);           // 33.5MB (reused as attn)
  __hip_bfloat16* kb = (__hip_bfloat16*)(ws + 75497472);           // 33.5MB (reused as partials)
  __hip_bfloat16* kT = (__hip_bfloat16*)(ws + 109051904);          // 33.5MB [bh*64+d][t]
  __hip_bfloat16* vT = (__hip_bfloat16*)(ws + 142606336);          // 33.5MB
  char* tail = ws + 176160768;
  float* pmax = (float*)tail;                       // 131072 f (bh*32 partials x 64 m)
  float* psum = pmax + 131072;
  float* cmax = psum + 131072;                      // 4096 f
  float* cinv = cmax + 4096;
  __hip_bfloat16* k_lat  = (__hip_bfloat16*)(cinv + 4096);   // 262144 bf16
  __hip_bfloat16* v_latT = k_lat + 262144;

  __hip_bfloat16* Pt   = xb;                // xb dead after projection GEMMs
  __hip_bfloat16* attn = qb;                // qb dead after stage2 (in-place ok)
  float* partials = (float*)kb;             // kb dead after stage1_logits

  cvt_bf16<<<16384, 256, 0, stream>>>(x, xb, 16777216);
  cvt_bf16<<<1024, 256, 0, stream>>>(Wq, Wb + 0 * 1048576, 1048576);
  cvt_bf16<<<1024, 256, 0, stream>>>(Wk, Wb + 1 * 1048576, 1048576);
  cvt_bf16<<<1024, 256, 0, stream>>>(Wv, Wb + 2 * 1048576, 1048576);
  cvt_bf16<<<1024, 256, 0, stream>>>(Wo, Wb + 3 * 1048576, 1048576);

  dim3 gg(128, 8);
  gemm128<1, 1><<<gg, 256, 0, stream>>>(xb, Wb + 0 * 1048576, qb, nullptr, cosT, sinT, 16384, 1024, 1024);
  gemm128<2, 1><<<gg, 256, 0, stream>>>(xb, Wb + 1 * 1048576, kb, kT, cosT, sinT, 16384, 1024, 1024);
  gemm128<3, 0><<<gg, 256, 0, stream>>>(xb, Wb + 2 * 1048576, nullptr, vT, nullptr, nullptr, 16384, 1024, 1024);

  dim3 sg(64, 8);
  stage1_logits<<<sg, 256, 0, stream>>>(kb, latent, mask, Pt, pmax, psum);
  stage1_reduce<<<16, 256, 0, stream>>>(pmax, psum, cmax, cinv);
  stage1_pvals2<<<8192, 256, 0, stream>>>(Pt, cmax, cinv);

  dim3 lg(64, 4);
  latgemm4<<<lg, 256, 0, stream>>>(Pt, kT, vT, partials);
  latreduce<<<2048, 256, 0, stream>>>(partials, k_lat, v_latT);

  stage2_attn<<<4096, 256, 0, stream>>>(qb, k_lat, v_latT, attn);
  gemm128<0, 0><<<gg, 256, 0, stream>>>(attn, Wb + 3 * 1048576, d_out, nullptr, nullptr, nullptr, 16384, 1024, 1024);
}

// Round 6
// 386.495 us; speedup vs baseline: 1.7327x; 1.0110x over previous
//
#include <hip/hip_runtime.h>
#include <hip/hip_bf16.h>
#include <stdint.h>

// MLAAttention on MI355X (gfx950).
// B=4 T=4096 D=1024 H=16 M=64 Dh=64. All inputs f32 (mask int32), output f32.
// R6: gemm128 -> 2-phase double-buffered K-loop (T3-minimum): STAGE(k+1) issued
//     before compute(k), counted s_waitcnt vmcnt(8) (never a full drain except
//     the last step), raw s_barrier pair, setprio around the MFMA cluster.
//     Targets the per-step HBM-latency drain (R5: MfmaUtil 18%, no pipe >25%).

#define DEV static __device__ __forceinline__

using short8 = __attribute__((ext_vector_type(8))) short;
using f32x4  = __attribute__((ext_vector_type(4))) float;

#define ZERO4 (f32x4){0.f, 0.f, 0.f, 0.f}

DEV float bf2f(unsigned short u) {
  union { unsigned int i; float f; } c; c.i = ((unsigned int)u) << 16; return c.f;
}
DEV unsigned short f2bf(float f) {
  __hip_bfloat16 h = __float2bfloat16(f);
  unsigned short u; __builtin_memcpy(&u, &h, 2); return u;
}
DEV f32x4 mfma16(short8 a, short8 b, f32x4 c) {
  return __builtin_amdgcn_mfma_f32_16x16x32_bf16(a, b, c, 0, 0, 0);
}
#define GLOAD_LDS16(G, L) __builtin_amdgcn_global_load_lds( \
    (const __attribute__((address_space(1))) void*)(G),     \
    (__attribute__((address_space(3))) void*)(L), 16, 0, 0)

// ---------------------------------------------------------------- convert
__global__ void cvt_bf16(const float* __restrict__ src,
                         __hip_bfloat16* __restrict__ dst, int n) {
  int i = (blockIdx.x * blockDim.x + threadIdx.x) * 4;
  if (i >= n) return;
  const float4 v = *(const float4*)(src + i);
  ushort4 o;
  o.x = f2bf(v.x); o.y = f2bf(v.y); o.z = f2bf(v.z); o.w = f2bf(v.w);
  *(ushort4*)(dst + i) = o;
}

// ---------------------------------------------------------------- GEMM 128x128
// C[M,N] = A[M,K] @ Bt[N,K]^T, bf16 in, f32 acc. 2-phase double-buffered.
// MODE: 0 = f32 normal; 1 = bf16 normal; 2 = bf16 normal + bf16 transposed;
//       3 = bf16 transposed only.
// ROPE: apply rotary (pairs along n; t = m&4095, d = n&63) to acc before stores.
// Transposed layout: Ct[((m>>12)*16 + (n>>6))*64 + (n&63)][t = m&4095]  (bf16)
template<int MODE, int ROPE>
__global__ __launch_bounds__(256)
void gemm128(const __hip_bfloat16* __restrict__ A,
             const __hip_bfloat16* __restrict__ Bt,
             void* __restrict__ Cout, __hip_bfloat16* __restrict__ Ct,
             const float* __restrict__ cosT, const float* __restrict__ sinT,
             int M, int N, int K) {
  __shared__ __hip_bfloat16 As[2][128 * 64];
  __shared__ __hip_bfloat16 Bs[2][128 * 64];
  const int tid = threadIdx.x;
  const int w = tid >> 6, l = tid & 63;
  const int rowA0 = blockIdx.x * 128;
  const int colB0 = blockIdx.y * 128;
  const int srow = w * 8 + (l >> 3);
  const int skk  = (l & 7) * 8;
  const __hip_bfloat16* Ab = A  + (size_t)(rowA0 + srow) * K + skk;
  const __hip_bfloat16* Bb = Bt + (size_t)(colB0 + srow) * K + skk;
  f32x4 acc[4][4];
#pragma unroll
  for (int i = 0; i < 4; ++i)
#pragma unroll
    for (int j = 0; j < 4; ++j) acc[i][j] = ZERO4;
  const int wr = (w >> 1) * 64, wc = (w & 1) * 64;
  const int NT = K >> 6;

#define G_STAGE(kt, buf)                                                        \
  {                                                                             \
    const int k0s = (kt) * 64;                                                  \
    _Pragma("unroll")                                                           \
    for (int i = 0; i < 4; ++i) {                                               \
      GLOAD_LDS16(Ab + (size_t)(i * 32) * K + k0s, &As[buf][i * 2048 + w * 512]); \
      GLOAD_LDS16(Bb + (size_t)(i * 32) * K + k0s, &Bs[buf][i * 2048 + w * 512]); \
    }                                                                           \
  }

  G_STAGE(0, 0);
  for (int kt = 0; kt < NT; ++kt) {
    const int cur = kt & 1;
    if (kt + 1 < NT) {
      G_STAGE(kt + 1, cur ^ 1);                      // prefetch into other slot
      asm volatile("s_waitcnt vmcnt(8)" ::: "memory");  // stage(kt) landed; kt+1 in flight
    } else {
      asm volatile("s_waitcnt vmcnt(0)" ::: "memory");
    }
    __builtin_amdgcn_s_barrier();                    // all waves' stage(kt) visible
    __builtin_amdgcn_s_setprio(1);
#pragma unroll
    for (int s = 0; s < 2; ++s) {
      short8 fa[4], fb[4];
#pragma unroll
      for (int i = 0; i < 4; ++i)
        fa[i] = *(const short8*)&As[cur][(wr + i * 16 + (l & 15)) * 64 + s * 32 + (l >> 4) * 8];
#pragma unroll
      for (int j = 0; j < 4; ++j)
        fb[j] = *(const short8*)&Bs[cur][(wc + j * 16 + (l & 15)) * 64 + s * 32 + (l >> 4) * 8];
#pragma unroll
      for (int i = 0; i < 4; ++i)
#pragma unroll
        for (int j = 0; j < 4; ++j)
          acc[i][j] = mfma16(fa[i], fb[j], acc[i][j]);
    }
    __builtin_amdgcn_s_setprio(0);
    __builtin_amdgcn_s_barrier();                    // reads of slot cur done before it is restaged
  }
#undef G_STAGE

  const int r0 = rowA0 + wr + (l >> 4) * 4;   // global row (m) base, +i*16+r
  const int c0 = colB0 + wc + (l & 15);       // global col (n), +j*16
  if (ROPE) {
#pragma unroll
    for (int i = 0; i < 4; ++i)
#pragma unroll
      for (int j = 0; j < 4; ++j)
#pragma unroll
        for (int r = 0; r < 4; ++r) {
          const int m = r0 + i * 16 + r;
          const int n = c0 + j * 16;
          const int t = m & 4095, d = n & 63;
          const float c = cosT[t * 64 + d];
          const float s = sinT[t * 64 + d];
          const float v = acc[i][j][r];
          const float other = __shfl_xor(v, 1, 64);
          acc[i][j][r] = v * c + ((n & 1) ? other : -other) * s;
        }
  }
  if (MODE <= 2) {
#pragma unroll
    for (int i = 0; i < 4; ++i)
#pragma unroll
      for (int j = 0; j < 4; ++j)
#pragma unroll
        for (int r = 0; r < 4; ++r) {
          const size_t idx = (size_t)(r0 + i * 16 + r) * N + (c0 + j * 16);
          if (MODE == 0) ((float*)Cout)[idx] = acc[i][j][r];
          else ((__hip_bfloat16*)Cout)[idx] = __float2bfloat16(acc[i][j][r]);
        }
  }
  if (MODE >= 2) {
#pragma unroll
    for (int i = 0; i < 4; ++i)
#pragma unroll
      for (int j = 0; j < 4; ++j) {
        const int m0 = r0 + i * 16;           // 4 contiguous t per lane
        const int n  = c0 + j * 16;
        const size_t row = (size_t)(((m0 >> 12) * 16 + (n >> 6)) * 64 + (n & 63));
        ushort4 pk;
        pk.x = f2bf(acc[i][j][0]); pk.y = f2bf(acc[i][j][1]);
        pk.z = f2bf(acc[i][j][2]); pk.w = f2bf(acc[i][j][3]);
        *(ushort4*)&Ct[row * 4096 + (m0 & 4095)] = pk;
      }
  }
}

// ---------------------------------------------------------------- stage1 logits (MFMA)
// S[bh][m][t] = 0.125 * sum_d latent[h][m][d]*K[b][t][h][d]  (bf16 store; -inf if masked)
// Fused online per-m (max,sum) partials: pmax/psum[(bh*8+chunk)*4 + wave][m].
__global__ __launch_bounds__(256)
void stage1_logits(const __hip_bfloat16* __restrict__ kmat,  // [B,T,H,64] (roped)
                   const float* __restrict__ latent,          // [H,64,64] f32
                   const int* __restrict__ mask,               // [B*T]
                   __hip_bfloat16* __restrict__ S,             // [bh][64][4096]
                   float* __restrict__ pmax, float* __restrict__ psum) {
  const int bh = blockIdx.x, chunk = blockIdx.y;
  const int b = bh >> 4, h = bh & 15;
  const int tid = threadIdx.x, w = tid >> 6, l = tid & 63;
  const int lr = l & 15, lg = l >> 4;
  short8 la[4][2];
#pragma unroll
  for (int n = 0; n < 4; ++n)
#pragma unroll
    for (int s = 0; s < 2; ++s) {
      const float* lp = &latent[((size_t)h * 64 + n * 16 + lr) * 64 + s * 32 + lg * 8];
      short8 f;
#pragma unroll
      for (int j = 0; j < 8; ++j) f[j] = (short)f2bf(lp[j]);
      la[n][s] = f;
    }
  float mx[16], sm[16];
#pragma unroll
  for (int i = 0; i < 16; ++i) { mx[i] = -3.0e38f; sm[i] = 0.f; }
  for (int tile = 0; tile < 8; ++tile) {
    const int t = chunk * 512 + tile * 64 + w * 16 + lr;
    const __hip_bfloat16* kp = &kmat[((size_t)(b * 4096 + t) * 16 + h) * 64 + lg * 8];
    const short8 kb0 = *(const short8*)kp;
    const short8 kb1 = *(const short8*)(kp + 32);
    const bool live = (mask[b * 4096 + t] != 0);
    f32x4 acc[4];
#pragma unroll
    for (int n = 0; n < 4; ++n) {
      acc[n] = ZERO4;
      acc[n] = mfma16(la[n][0], kb0, acc[n]);
      acc[n] = mfma16(la[n][1], kb1, acc[n]);
    }
#pragma unroll
    for (int n = 0; n < 4; ++n)
#pragma unroll
      for (int r = 0; r < 4; ++r) {
        const float v = acc[n][r] * 0.125f;
        const int m = n * 16 + lg * 4 + r;
        unsigned short sv = live ? f2bf(v) : (unsigned short)0xFF80;  // -inf
        ((unsigned short*)S)[((size_t)bh * 64 + m) * 4096 + t] = sv;
        if (live) {
          const int idx = n * 4 + r;
          const float nm = fmaxf(mx[idx], v);
          sm[idx] = sm[idx] * __expf(mx[idx] - nm) + __expf(v - nm);
          mx[idx] = nm;
        }
      }
  }
#pragma unroll
  for (int o = 1; o < 16; o <<= 1)
#pragma unroll
    for (int i = 0; i < 16; ++i) {
      const float omx = __shfl_xor(mx[i], o, 64);
      const float osm = __shfl_xor(sm[i], o, 64);
      const float nm = fmaxf(mx[i], omx);
      sm[i] = sm[i] * __expf(mx[i] - nm) + osm * __expf(omx - nm);
      mx[i] = nm;
    }
  if (lr == 0) {
    const size_t pb = ((size_t)(bh * 8 + chunk) * 4 + w) * 64;
#pragma unroll
    for (int n = 0; n < 4; ++n)
#pragma unroll
      for (int r = 0; r < 4; ++r) {
        const int m = n * 16 + lg * 4 + r;
        pmax[pb + m] = mx[n * 4 + r];
        psum[pb + m] = sm[n * 4 + r];
      }
  }
}

// combine 32 partials per (bh,m)
__global__ void stage1_reduce(const float* __restrict__ pmax,
                              const float* __restrict__ psum,
                              float* __restrict__ cmax, float* __restrict__ cinv) {
  const int i = blockIdx.x * 256 + threadIdx.x;
  if (i >= 4096) return;
  const int bh = i >> 6, m = i & 63;
  float mx = -3.0e38f;
#pragma unroll
  for (int c = 0; c < 32; ++c)
    mx = fmaxf(mx, pmax[((size_t)bh * 32 + c) * 64 + m]);
  float sm = 0.f;
#pragma unroll
  for (int c = 0; c < 32; ++c)
    sm += psum[((size_t)bh * 32 + c) * 64 + m] *
          __expf(pmax[((size_t)bh * 32 + c) * 64 + m] - mx);
  cmax[i] = mx;
  cinv[i] = 1.f / sm;
}

// In-place: Pt[i] = exp(logit - cmax)*cinv. Masked logits are -inf -> exp = 0.
__global__ void stage1_pvals2(__hip_bfloat16* __restrict__ Pt,
                              const float* __restrict__ cmax,
                              const float* __restrict__ cinv) {
  const size_t i = ((size_t)blockIdx.x * 256 + threadIdx.x) * 8;  // 16,777,216 total
  const int bh = (int)(i >> 18);
  const int m  = (int)((i >> 12) & 63);
  const float cm = cmax[bh * 64 + m], ci = cinv[bh * 64 + m];
  short8 sv = *(short8*)&Pt[i];
  short8 ov;
#pragma unroll
  for (int j = 0; j < 8; ++j) {
    const float p = __expf(bf2f((unsigned short)sv[j]) - cm) * ci;
    ov[j] = (short)f2bf(p);
  }
  *(short8*)&Pt[i] = ov;
}

// ---------------------------------------------------------------- latent GEMM v4
__global__ __launch_bounds__(256)
void latgemm4(const __hip_bfloat16* __restrict__ Pt,
              const __hip_bfloat16* __restrict__ kT,
              const __hip_bfloat16* __restrict__ vT,
              float* __restrict__ partials) {   // [slice][bh][8192]
  const int bh = blockIdx.x;
  const int tid = threadIdx.x, w = tid >> 6, l = tid & 63;
  const int slice = blockIdx.y * 4 + w;
  const int lr = l & 15;            // frag row
  const int lk = (l >> 4) * 8;      // frag k-offset
  const size_t base = (size_t)bh * 64 * 4096;
  f32x4 ak[4][4], av[4][4];
#pragma unroll
  for (int i = 0; i < 4; ++i)
#pragma unroll
    for (int j = 0; j < 4; ++j) { ak[i][j] = ZERO4; av[i][j] = ZERO4; }
  for (int ks = 0; ks < 8; ++ks) {
    const int t = slice * 256 + ks * 32 + lk;
    short8 fp[4], fk[4], fv[4];
#pragma unroll
    for (int i = 0; i < 4; ++i) {
      const size_t ro = base + (size_t)(i * 16 + lr) * 4096 + t;
      fp[i] = *(const short8*)&Pt[ro];
      fk[i] = *(const short8*)&kT[ro];
      fv[i] = *(const short8*)&vT[ro];
    }
#pragma unroll
    for (int i = 0; i < 4; ++i)
#pragma unroll
      for (int j = 0; j < 4; ++j) {
        ak[i][j] = mfma16(fp[i], fk[j], ak[i][j]);   // C[m][d]
        av[i][j] = mfma16(fv[i], fp[j], av[i][j]);   // C[d][m]
      }
  }
  float* pk = partials + ((size_t)(slice * 64 + bh)) * 8192;
#pragma unroll
  for (int i = 0; i < 4; ++i)
#pragma unroll
    for (int j = 0; j < 4; ++j)
#pragma unroll
      for (int r = 0; r < 4; ++r) {
        const int row = i * 16 + 4 * (l >> 4) + r;
        const int col = j * 16 + lr;
        pk[(size_t)row * 64 + col]        = ak[i][j][r];
        pk[4096 + (size_t)row * 64 + col] = av[i][j][r];
      }
}

// Sum 16 slice-partials -> bf16 k_lat [bh][m][d] and v_latT [bh][d][m]
__global__ void latreduce(const float* __restrict__ partials,
                          __hip_bfloat16* __restrict__ k_lat,
                          __hip_bfloat16* __restrict__ v_latT) {
  const int i = blockIdx.x * 256 + threadIdx.x;   // 524288
  const int bh = i >> 13, off = i & 8191;
  float sm = 0.f;
#pragma unroll
  for (int c = 0; c < 16; ++c)
    sm += partials[((size_t)(c * 64 + bh)) * 8192 + off];
  if (off < 4096) k_lat[(size_t)bh * 4096 + off] = __float2bfloat16(sm);
  else            v_latT[(size_t)bh * 4096 + (off - 4096)] = __float2bfloat16(sm);
}

// ---------------------------------------------------------------- stage2 fused
__global__ __launch_bounds__(256)
void stage2_attn(const __hip_bfloat16* __restrict__ q,
                 const __hip_bfloat16* __restrict__ k_lat,
                 const __hip_bfloat16* __restrict__ v_latT,
                 __hip_bfloat16* __restrict__ attn) {
  __shared__ unsigned short Pl[4][16][64];
  const int bid = blockIdx.x;
  const int bh = bid >> 6, tt = (bid & 63) * 64;
  const int b = bh >> 4, h = bh & 15;
  const int tid = threadIdx.x, w = tid >> 6, l = tid & 63;
  const size_t qoff = ((size_t)(b * 4096 + tt + w * 16 + (l & 15)) * 16 + h) * 64;
  const short8 a0 = *(const short8*)&q[qoff + (l >> 4) * 8];
  const short8 a1 = *(const short8*)&q[qoff + 32 + (l >> 4) * 8];
  f32x4 att[4];
#pragma unroll
  for (int n = 0; n < 4; ++n) att[n] = ZERO4;
#pragma unroll
  for (int n = 0; n < 4; ++n) {
    const __hip_bfloat16* kl = &k_lat[((size_t)bh * 64 + n * 16 + (l & 15)) * 64];
    const short8 b0 = *(const short8*)&kl[(l >> 4) * 8];
    const short8 b1 = *(const short8*)&kl[32 + (l >> 4) * 8];
    att[n] = mfma16(a0, b0, att[n]);
    att[n] = mfma16(a1, b1, att[n]);
  }
  float p[4][4];
#pragma unroll
  for (int r = 0; r < 4; ++r) {
    const float v0 = att[0][r] * 0.125f, v1 = att[1][r] * 0.125f;
    const float v2 = att[2][r] * 0.125f, v3 = att[3][r] * 0.125f;
    float mxv = fmaxf(fmaxf(v0, v1), fmaxf(v2, v3));
#pragma unroll
    for (int o = 1; o < 16; o <<= 1) mxv = fmaxf(mxv, __shfl_xor(mxv, o, 64));
    const float e0 = __expf(v0 - mxv), e1 = __expf(v1 - mxv);
    const float e2 = __expf(v2 - mxv), e3 = __expf(v3 - mxv);
    float sum = e0 + e1 + e2 + e3;
#pragma unroll
    for (int o = 1; o < 16; o <<= 1) sum += __shfl_xor(sum, o, 64);
    const float inv = 1.f / sum;
    p[0][r] = e0 * inv; p[1][r] = e1 * inv; p[2][r] = e2 * inv; p[3][r] = e3 * inv;
  }
#pragma unroll
  for (int n = 0; n < 4; ++n)
#pragma unroll
    for (int r = 0; r < 4; ++r) {
      const int row = 4 * (l >> 4) + r;
      const int col = n * 16 + (l & 15);
      Pl[w][row][col ^ ((row & 7) << 3)] = f2bf(p[n][r]);
    }
  __syncthreads();
  const int arow = l & 15;
  const short8 pa0 = *(const short8*)&Pl[w][arow][(((l >> 4) + 0) ^ (arow & 7)) * 8];
  const short8 pa1 = *(const short8*)&Pl[w][arow][(((l >> 4) + 4) ^ (arow & 7)) * 8];
  f32x4 ov[4];
#pragma unroll
  for (int n = 0; n < 4; ++n) ov[n] = ZERO4;
#pragma unroll
  for (int n = 0; n < 4; ++n) {
    const __hip_bfloat16* vt = &v_latT[((size_t)bh * 64 + n * 16 + (l & 15)) * 64];
    const short8 b0 = *(const short8*)&vt[(l >> 4) * 8];
    const short8 b1 = *(const short8*)&vt[32 + (l >> 4) * 8];
    ov[n] = mfma16(pa0, b0, ov[n]);
    ov[n] = mfma16(pa1, b1, ov[n]);
  }
#pragma unroll
  for (int n = 0; n < 4; ++n) {
    const int d = n * 16 + (l & 15);
#pragma unroll
    for (int r = 0; r < 4; ++r) {
      const int trow = tt + w * 16 + 4 * (l >> 4) + r;
      attn[((size_t)(b * 4096 + trow) * 16 + h) * 64 + d] = __float2bfloat16(ov[n][r]);
    }
  }
}

// ---------------------------------------------------------------- launch
extern "C" void kernel_launch(void* const* d_in, const int* in_sizes, int n_in,
                              void* d_out, int out_size, void* d_ws, size_t ws_size,
                              hipStream_t stream) {
  const float* x      = (const float*)d_in[0];
  const float* Wq     = (const float*)d_in[1];
  const float* Wk     = (const float*)d_in[2];
  const float* Wv     = (const float*)d_in[3];
  const float* Wo     = (const float*)d_in[4];
  const float* latent = (const float*)d_in[5];
  const float* cosT   = (const float*)d_in[6];
  const float* sinT   = (const float*)d_in[7];
  const int*   mask   = (const int*)d_in[8];

  char* ws = (char*)d_ws;
  __hip_bfloat16* xb = (__hip_bfloat16*)ws;                        // 33.5MB (reused as Pt/S)
  __hip_bfloat16* Wb = (__hip_bfloat16*)(ws + 33554432);           // 8.4MB
  __hip_bfloat16* qb = (__hip_bfloat16*)(ws + 41943040);           // 33.5MB (reused as attn)
  __hip_bfloat16* kb = (__hip_bfloat16*)(ws + 75497472);           // 33.5MB (reused as partials)
  __hip_bfloat16* kT = (__hip_bfloat16*)(ws + 109051904);          // 33.5MB [bh*64+d][t]
  __hip_bfloat16* vT = (__hip_bfloat16*)(ws + 142606336);          // 33.5MB
  char* tail = ws + 176160768;
  float* pmax = (float*)tail;                       // 131072 f
  float* psum = pmax + 131072;
  float* cmax = psum + 131072;                      // 4096 f
  float* cinv = cmax + 4096;
  __hip_bfloat16* k_lat  = (__hip_bfloat16*)(cinv + 4096);   // 262144 bf16
  __hip_bfloat16* v_latT = k_lat + 262144;

  __hip_bfloat16* Pt   = xb;                // xb dead after projection GEMMs
  __hip_bfloat16* attn = qb;                // qb dead after stage2 (in-place ok)
  float* partials = (float*)kb;             // kb dead after stage1_logits

  cvt_bf16<<<16384, 256, 0, stream>>>(x, xb, 16777216);
  cvt_bf16<<<1024, 256, 0, stream>>>(Wq, Wb + 0 * 1048576, 1048576);
  cvt_bf16<<<1024, 256, 0, stream>>>(Wk, Wb + 1 * 1048576, 1048576);
  cvt_bf16<<<1024, 256, 0, stream>>>(Wv, Wb + 2 * 1048576, 1048576);
  cvt_bf16<<<1024, 256, 0, stream>>>(Wo, Wb + 3 * 1048576, 1048576);

  dim3 gg(128, 8);
  gemm128<1, 1><<<gg, 256, 0, stream>>>(xb, Wb + 0 * 1048576, qb, nullptr, cosT, sinT, 16384, 1024, 1024);
  gemm128<2, 1><<<gg, 256, 0, stream>>>(xb, Wb + 1 * 1048576, kb, kT, cosT, sinT, 16384, 1024, 1024);
  gemm128<3, 0><<<gg, 256, 0, stream>>>(xb, Wb + 2 * 1048576, nullptr, vT, nullptr, nullptr, 16384, 1024, 1024);

  dim3 sg(64, 8);
  stage1_logits<<<sg, 256, 0, stream>>>(kb, latent, mask, Pt, pmax, psum);
  stage1_reduce<<<16, 256, 0, stream>>>(pmax, psum, cmax, cinv);
  stage1_pvals2<<<8192, 256, 0, stream>>>(Pt, cmax, cinv);

  dim3 lg(64, 4);
  latgemm4<<<lg, 256, 0, stream>>>(Pt, kT, vT, partials);
  latreduce<<<2048, 256, 0, stream>>>(partials, k_lat, v_latT);

  stage2_attn<<<4096, 256, 0, stream>>>(qb, k_lat, v_latT, attn);
  gemm128<0, 0><<<gg, 256, 0, stream>>>(attn, Wb + 3 * 1048576, d_out, nullptr, nullptr, nullptr, 16384, 1024, 1024);
}

// Round 7
// 360.056 us; speedup vs baseline: 1.8599x; 1.0734x over previous
//
#include <hip/hip_runtime.h>
#include <hip/hip_bf16.h>
#include <stdint.h>

// MLAAttention on MI355X (gfx950).
// B=4 T=4096 D=1024 H=16 M=64 Dh=64. All inputs f32 (mask int32), output f32.
// R7: gemm -> 256x256 tile, 8 waves (512 thr), same verified 2-phase counted-vmcnt
//     structure (R6 showed schedule tweaks null at 2ph; tile size is the lever at
//     K=1024). stage1_pvals2 fused into latgemm5 (exp applied in-register).

#define DEV static __device__ __forceinline__

using short8 = __attribute__((ext_vector_type(8))) short;
using f32x4  = __attribute__((ext_vector_type(4))) float;

#define ZERO4 (f32x4){0.f, 0.f, 0.f, 0.f}

DEV float bf2f(unsigned short u) {
  union { unsigned int i; float f; } c; c.i = ((unsigned int)u) << 16; return c.f;
}
DEV unsigned short f2bf(float f) {
  __hip_bfloat16 h = __float2bfloat16(f);
  unsigned short u; __builtin_memcpy(&u, &h, 2); return u;
}
DEV f32x4 mfma16(short8 a, short8 b, f32x4 c) {
  return __builtin_amdgcn_mfma_f32_16x16x32_bf16(a, b, c, 0, 0, 0);
}
#define GLOAD_LDS16(G, L) __builtin_amdgcn_global_load_lds( \
    (const __attribute__((address_space(1))) void*)(G),     \
    (__attribute__((address_space(3))) void*)(L), 16, 0, 0)

// ---------------------------------------------------------------- convert
__global__ void cvt_bf16(const float* __restrict__ src,
                         __hip_bfloat16* __restrict__ dst, int n) {
  int i = (blockIdx.x * blockDim.x + threadIdx.x) * 4;
  if (i >= n) return;
  const float4 v = *(const float4*)(src + i);
  ushort4 o;
  o.x = f2bf(v.x); o.y = f2bf(v.y); o.z = f2bf(v.z); o.w = f2bf(v.w);
  *(ushort4*)(dst + i) = o;
}

// ---------------------------------------------------------------- GEMM 256x256
// C[M,N] = A[M,K] @ Bt[N,K]^T, bf16 in, f32 acc. 8 waves (2M x 4N), 2-phase
// double-buffered K-loop with counted vmcnt (stage k+1 in flight over compute k).
// MODE: 0 = f32 normal; 1 = bf16 normal; 2 = bf16 normal + bf16 transposed;
//       3 = bf16 transposed only.
// ROPE: apply rotary (pairs along n; t = m&4095, d = n&63) to acc before stores.
// Transposed layout: Ct[((m>>12)*16 + (n>>6))*64 + (n&63)][t = m&4095]  (bf16)
template<int MODE, int ROPE>
__global__ __launch_bounds__(512, 2)
void gemm256(const __hip_bfloat16* __restrict__ A,
             const __hip_bfloat16* __restrict__ Bt,
             void* __restrict__ Cout, __hip_bfloat16* __restrict__ Ct,
             const float* __restrict__ cosT, const float* __restrict__ sinT,
             int M, int N, int K) {
  __shared__ __hip_bfloat16 As[2][256 * 64];
  __shared__ __hip_bfloat16 Bs[2][256 * 64];
  const int tid = threadIdx.x;
  const int w = tid >> 6, l = tid & 63;
  const int lr = l & 15, lg = l >> 4;
  const int rowA0 = blockIdx.x * 256;
  const int colB0 = blockIdx.y * 256;
  const int srow = w * 8 + (l >> 3);      // staging row within 64-row round
  const int skk  = (l & 7) * 8;           // staging k offset (8 bf16 = 16B)
  const __hip_bfloat16* Ab = A  + (size_t)(rowA0 + srow) * K + skk;
  const __hip_bfloat16* Bb = Bt + (size_t)(colB0 + srow) * K + skk;
  f32x4 acc[8][4];
#pragma unroll
  for (int i = 0; i < 8; ++i)
#pragma unroll
    for (int j = 0; j < 4; ++j) acc[i][j] = ZERO4;
  const int wr = (w >> 2) * 128;          // wave M-offset (0 or 128)
  const int wc = (w & 3) * 64;            // wave N-offset (0,64,128,192)
  const int NT = K >> 6;

#define G_STAGE(kt, buf)                                                          \
  {                                                                               \
    const int k0s = (kt) * 64;                                                    \
    _Pragma("unroll")                                                             \
    for (int i = 0; i < 4; ++i) {                                                 \
      GLOAD_LDS16(Ab + (size_t)(i * 64) * K + k0s, &As[buf][i * 4096 + w * 512]); \
      GLOAD_LDS16(Bb + (size_t)(i * 64) * K + k0s, &Bs[buf][i * 4096 + w * 512]); \
    }                                                                             \
  }

  G_STAGE(0, 0);
  for (int kt = 0; kt < NT; ++kt) {
    const int cur = kt & 1;
    if (kt + 1 < NT) {
      G_STAGE(kt + 1, cur ^ 1);                         // prefetch other slot
      asm volatile("s_waitcnt vmcnt(8)" ::: "memory");  // own stage(kt) landed
    } else {
      asm volatile("s_waitcnt vmcnt(0)" ::: "memory");
    }
    __builtin_amdgcn_s_barrier();                       // all waves' stage(kt) visible
    __builtin_amdgcn_s_setprio(1);
#pragma unroll
    for (int s = 0; s < 2; ++s) {
      short8 fa[8], fb[4];
#pragma unroll
      for (int i = 0; i < 8; ++i)
        fa[i] = *(const short8*)&As[cur][(wr + i * 16 + lr) * 64 + s * 32 + lg * 8];
#pragma unroll
      for (int j = 0; j < 4; ++j)
        fb[j] = *(const short8*)&Bs[cur][(wc + j * 16 + lr) * 64 + s * 32 + lg * 8];
#pragma unroll
      for (int i = 0; i < 8; ++i)
#pragma unroll
        for (int j = 0; j < 4; ++j)
          acc[i][j] = mfma16(fa[i], fb[j], acc[i][j]);
    }
    __builtin_amdgcn_s_setprio(0);
    __builtin_amdgcn_s_barrier();                       // slot reads done before restage
  }
#undef G_STAGE

  const int r0 = rowA0 + wr + lg * 4;     // global row (m) base, +i*16+r
  const int c0 = colB0 + wc + lr;         // global col (n), +j*16
  if (ROPE) {
#pragma unroll
    for (int i = 0; i < 8; ++i)
#pragma unroll
      for (int j = 0; j < 4; ++j)
#pragma unroll
        for (int r = 0; r < 4; ++r) {
          const int m = r0 + i * 16 + r;
          const int n = c0 + j * 16;
          const int t = m & 4095, d = n & 63;
          const float c = cosT[t * 64 + d];
          const float s = sinT[t * 64 + d];
          const float v = acc[i][j][r];
          const float other = __shfl_xor(v, 1, 64);
          acc[i][j][r] = v * c + ((n & 1) ? other : -other) * s;
        }
  }
  if (MODE <= 2) {
#pragma unroll
    for (int i = 0; i < 8; ++i)
#pragma unroll
      for (int j = 0; j < 4; ++j)
#pragma unroll
        for (int r = 0; r < 4; ++r) {
          const size_t idx = (size_t)(r0 + i * 16 + r) * N + (c0 + j * 16);
          if (MODE == 0) ((float*)Cout)[idx] = acc[i][j][r];
          else ((__hip_bfloat16*)Cout)[idx] = __float2bfloat16(acc[i][j][r]);
        }
  }
  if (MODE >= 2) {
#pragma unroll
    for (int i = 0; i < 8; ++i)
#pragma unroll
      for (int j = 0; j < 4; ++j) {
        const int m0 = r0 + i * 16;           // 4 contiguous t per lane
        const int n  = c0 + j * 16;
        const size_t row = (size_t)(((m0 >> 12) * 16 + (n >> 6)) * 64 + (n & 63));
        ushort4 pk;
        pk.x = f2bf(acc[i][j][0]); pk.y = f2bf(acc[i][j][1]);
        pk.z = f2bf(acc[i][j][2]); pk.w = f2bf(acc[i][j][3]);
        *(ushort4*)&Ct[row * 4096 + (m0 & 4095)] = pk;
      }
  }
}

// ---------------------------------------------------------------- stage1 logits (MFMA)
// S[bh][m][t] = 0.125 * sum_d latent[h][m][d]*K[b][t][h][d]  (bf16 store; -inf if masked)
// Fused online per-m (max,sum) partials: pmax/psum[(bh*8+chunk)*4 + wave][m].
__global__ __launch_bounds__(256)
void stage1_logits(const __hip_bfloat16* __restrict__ kmat,  // [B,T,H,64] (roped)
                   const float* __restrict__ latent,          // [H,64,64] f32
                   const int* __restrict__ mask,               // [B*T]
                   __hip_bfloat16* __restrict__ S,             // [bh][64][4096]
                   float* __restrict__ pmax, float* __restrict__ psum) {
  const int bh = blockIdx.x, chunk = blockIdx.y;
  const int b = bh >> 4, h = bh & 15;
  const int tid = threadIdx.x, w = tid >> 6, l = tid & 63;
  const int lr = l & 15, lg = l >> 4;
  short8 la[4][2];
#pragma unroll
  for (int n = 0; n < 4; ++n)
#pragma unroll
    for (int s = 0; s < 2; ++s) {
      const float* lp = &latent[((size_t)h * 64 + n * 16 + lr) * 64 + s * 32 + lg * 8];
      short8 f;
#pragma unroll
      for (int j = 0; j < 8; ++j) f[j] = (short)f2bf(lp[j]);
      la[n][s] = f;
    }
  float mx[16], sm[16];
#pragma unroll
  for (int i = 0; i < 16; ++i) { mx[i] = -3.0e38f; sm[i] = 0.f; }
  for (int tile = 0; tile < 8; ++tile) {
    const int t = chunk * 512 + tile * 64 + w * 16 + lr;
    const __hip_bfloat16* kp = &kmat[((size_t)(b * 4096 + t) * 16 + h) * 64 + lg * 8];
    const short8 kb0 = *(const short8*)kp;
    const short8 kb1 = *(const short8*)(kp + 32);
    const bool live = (mask[b * 4096 + t] != 0);
    f32x4 acc[4];
#pragma unroll
    for (int n = 0; n < 4; ++n) {
      acc[n] = ZERO4;
      acc[n] = mfma16(la[n][0], kb0, acc[n]);
      acc[n] = mfma16(la[n][1], kb1, acc[n]);
    }
#pragma unroll
    for (int n = 0; n < 4; ++n)
#pragma unroll
      for (int r = 0; r < 4; ++r) {
        const float v = acc[n][r] * 0.125f;
        const int m = n * 16 + lg * 4 + r;
        unsigned short sv = live ? f2bf(v) : (unsigned short)0xFF80;  // -inf
        ((unsigned short*)S)[((size_t)bh * 64 + m) * 4096 + t] = sv;
        if (live) {
          const int idx = n * 4 + r;
          const float nm = fmaxf(mx[idx], v);
          sm[idx] = sm[idx] * __expf(mx[idx] - nm) + __expf(v - nm);
          mx[idx] = nm;
        }
      }
  }
#pragma unroll
  for (int o = 1; o < 16; o <<= 1)
#pragma unroll
    for (int i = 0; i < 16; ++i) {
      const float omx = __shfl_xor(mx[i], o, 64);
      const float osm = __shfl_xor(sm[i], o, 64);
      const float nm = fmaxf(mx[i], omx);
      sm[i] = sm[i] * __expf(mx[i] - nm) + osm * __expf(omx - nm);
      mx[i] = nm;
    }
  if (lr == 0) {
    const size_t pb = ((size_t)(bh * 8 + chunk) * 4 + w) * 64;
#pragma unroll
    for (int n = 0; n < 4; ++n)
#pragma unroll
      for (int r = 0; r < 4; ++r) {
        const int m = n * 16 + lg * 4 + r;
        pmax[pb + m] = mx[n * 4 + r];
        psum[pb + m] = sm[n * 4 + r];
      }
  }
}

// combine 32 partials per (bh,m)
__global__ void stage1_reduce(const float* __restrict__ pmax,
                              const float* __restrict__ psum,
                              float* __restrict__ cmax, float* __restrict__ cinv) {
  const int i = blockIdx.x * 256 + threadIdx.x;
  if (i >= 4096) return;
  const int bh = i >> 6, m = i & 63;
  float mx = -3.0e38f;
#pragma unroll
  for (int c = 0; c < 32; ++c)
    mx = fmaxf(mx, pmax[((size_t)bh * 32 + c) * 64 + m]);
  float sm = 0.f;
#pragma unroll
  for (int c = 0; c < 32; ++c)
    sm += psum[((size_t)bh * 32 + c) * 64 + m] *
          __expf(pmax[((size_t)bh * 32 + c) * 64 + m] - mx);
  cmax[i] = mx;
  cinv[i] = 1.f / sm;
}

// ---------------------------------------------------------------- latent GEMM v5
// Direct-from-global register-fragment MFMA reduction with FUSED softmax-exp:
// fp = bf16(exp(S - cmax)*cinv) computed in-register from raw logits S.
// k_lat_part[m,d] = sum_t P[m,t]*kT[d,t]; v_latT_part[d,m] = sum_t vT[d,t]*P[m,t].
__global__ __launch_bounds__(256)
void latgemm5(const __hip_bfloat16* __restrict__ S,   // logits [bh][64][4096]
              const __hip_bfloat16* __restrict__ kT,
              const __hip_bfloat16* __restrict__ vT,
              const float* __restrict__ cmax, const float* __restrict__ cinv,
              float* __restrict__ partials) {   // [slice][bh][8192]
  const int bh = blockIdx.x;
  const int tid = threadIdx.x, w = tid >> 6, l = tid & 63;
  const int slice = blockIdx.y * 4 + w;
  const int lr = l & 15;            // frag row
  const int lk = (l >> 4) * 8;      // frag k-offset
  const size_t base = (size_t)bh * 64 * 4096;
  float cm[4], ci[4];
#pragma unroll
  for (int i = 0; i < 4; ++i) {
    cm[i] = cmax[bh * 64 + i * 16 + lr];
    ci[i] = cinv[bh * 64 + i * 16 + lr];
  }
  f32x4 ak[4][4], av[4][4];
#pragma unroll
  for (int i = 0; i < 4; ++i)
#pragma unroll
    for (int j = 0; j < 4; ++j) { ak[i][j] = ZERO4; av[i][j] = ZERO4; }
  for (int ks = 0; ks < 8; ++ks) {
    const int t = slice * 256 + ks * 32 + lk;
    short8 fp[4], fk[4], fv[4];
#pragma unroll
    for (int i = 0; i < 4; ++i) {
      const size_t ro = base + (size_t)(i * 16 + lr) * 4096 + t;
      const short8 sv = *(const short8*)&S[ro];
      short8 p;
#pragma unroll
      for (int j = 0; j < 8; ++j)
        p[j] = (short)f2bf(__expf(bf2f((unsigned short)sv[j]) - cm[i]) * ci[i]);
      fp[i] = p;
      fk[i] = *(const short8*)&kT[ro];
      fv[i] = *(const short8*)&vT[ro];
    }
#pragma unroll
    for (int i = 0; i < 4; ++i)
#pragma unroll
      for (int j = 0; j < 4; ++j) {
        ak[i][j] = mfma16(fp[i], fk[j], ak[i][j]);   // C[m][d]
        av[i][j] = mfma16(fv[i], fp[j], av[i][j]);   // C[d][m]
      }
  }
  float* pk = partials + ((size_t)(slice * 64 + bh)) * 8192;
#pragma unroll
  for (int i = 0; i < 4; ++i)
#pragma unroll
    for (int j = 0; j < 4; ++j)
#pragma unroll
      for (int r = 0; r < 4; ++r) {
        const int row = i * 16 + 4 * (l >> 4) + r;
        const int col = j * 16 + lr;
        pk[(size_t)row * 64 + col]        = ak[i][j][r];
        pk[4096 + (size_t)row * 64 + col] = av[i][j][r];
      }
}

// Sum 16 slice-partials -> bf16 k_lat [bh][m][d] and v_latT [bh][d][m]
__global__ void latreduce(const float* __restrict__ partials,
                          __hip_bfloat16* __restrict__ k_lat,
                          __hip_bfloat16* __restrict__ v_latT) {
  const int i = blockIdx.x * 256 + threadIdx.x;   // 524288
  const int bh = i >> 13, off = i & 8191;
  float sm = 0.f;
#pragma unroll
  for (int c = 0; c < 16; ++c)
    sm += partials[((size_t)(c * 64 + bh)) * 8192 + off];
  if (off < 4096) k_lat[(size_t)bh * 4096 + off] = __float2bfloat16(sm);
  else            v_latT[(size_t)bh * 4096 + (off - 4096)] = __float2bfloat16(sm);
}

// ---------------------------------------------------------------- stage2 fused
__global__ __launch_bounds__(256)
void stage2_attn(const __hip_bfloat16* __restrict__ q,
                 const __hip_bfloat16* __restrict__ k_lat,
                 const __hip_bfloat16* __restrict__ v_latT,
                 __hip_bfloat16* __restrict__ attn) {
  __shared__ unsigned short Pl[4][16][64];
  const int bid = blockIdx.x;
  const int bh = bid >> 6, tt = (bid & 63) * 64;
  const int b = bh >> 4, h = bh & 15;
  const int tid = threadIdx.x, w = tid >> 6, l = tid & 63;
  const size_t qoff = ((size_t)(b * 4096 + tt + w * 16 + (l & 15)) * 16 + h) * 64;
  const short8 a0 = *(const short8*)&q[qoff + (l >> 4) * 8];
  const short8 a1 = *(const short8*)&q[qoff + 32 + (l >> 4) * 8];
  f32x4 att[4];
#pragma unroll
  for (int n = 0; n < 4; ++n) att[n] = ZERO4;
#pragma unroll
  for (int n = 0; n < 4; ++n) {
    const __hip_bfloat16* kl = &k_lat[((size_t)bh * 64 + n * 16 + (l & 15)) * 64];
    const short8 b0 = *(const short8*)&kl[(l >> 4) * 8];
    const short8 b1 = *(const short8*)&kl[32 + (l >> 4) * 8];
    att[n] = mfma16(a0, b0, att[n]);
    att[n] = mfma16(a1, b1, att[n]);
  }
  float p[4][4];
#pragma unroll
  for (int r = 0; r < 4; ++r) {
    const float v0 = att[0][r] * 0.125f, v1 = att[1][r] * 0.125f;
    const float v2 = att[2][r] * 0.125f, v3 = att[3][r] * 0.125f;
    float mxv = fmaxf(fmaxf(v0, v1), fmaxf(v2, v3));
#pragma unroll
    for (int o = 1; o < 16; o <<= 1) mxv = fmaxf(mxv, __shfl_xor(mxv, o, 64));
    const float e0 = __expf(v0 - mxv), e1 = __expf(v1 - mxv);
    const float e2 = __expf(v2 - mxv), e3 = __expf(v3 - mxv);
    float sum = e0 + e1 + e2 + e3;
#pragma unroll
    for (int o = 1; o < 16; o <<= 1) sum += __shfl_xor(sum, o, 64);
    const float inv = 1.f / sum;
    p[0][r] = e0 * inv; p[1][r] = e1 * inv; p[2][r] = e2 * inv; p[3][r] = e3 * inv;
  }
#pragma unroll
  for (int n = 0; n < 4; ++n)
#pragma unroll
    for (int r = 0; r < 4; ++r) {
      const int row = 4 * (l >> 4) + r;
      const int col = n * 16 + (l & 15);
      Pl[w][row][col ^ ((row & 7) << 3)] = f2bf(p[n][r]);
    }
  __syncthreads();
  const int arow = l & 15;
  const short8 pa0 = *(const short8*)&Pl[w][arow][(((l >> 4) + 0) ^ (arow & 7)) * 8];
  const short8 pa1 = *(const short8*)&Pl[w][arow][(((l >> 4) + 4) ^ (arow & 7)) * 8];
  f32x4 ov[4];
#pragma unroll
  for (int n = 0; n < 4; ++n) ov[n] = ZERO4;
#pragma unroll
  for (int n = 0; n < 4; ++n) {
    const __hip_bfloat16* vt = &v_latT[((size_t)bh * 64 + n * 16 + (l & 15)) * 64];
    const short8 b0 = *(const short8*)&vt[(l >> 4) * 8];
    const short8 b1 = *(const short8*)&vt[32 + (l >> 4) * 8];
    ov[n] = mfma16(pa0, b0, ov[n]);
    ov[n] = mfma16(pa1, b1, ov[n]);
  }
#pragma unroll
  for (int n = 0; n < 4; ++n) {
    const int d = n * 16 + (l & 15);
#pragma unroll
    for (int r = 0; r < 4; ++r) {
      const int trow = tt + w * 16 + 4 * (l >> 4) + r;
      attn[((size_t)(b * 4096 + trow) * 16 + h) * 64 + d] = __float2bfloat16(ov[n][r]);
    }
  }
}

// ---------------------------------------------------------------- launch
extern "C" void kernel_launch(void* const* d_in, const int* in_sizes, int n_in,
                              void* d_out, int out_size, void* d_ws, size_t ws_size,
                              hipStream_t stream) {
  const float* x      = (const float*)d_in[0];
  const float* Wq     = (const float*)d_in[1];
  const float* Wk     = (const float*)d_in[2];
  const float* Wv     = (const float*)d_in[3];
  const float* Wo     = (const float*)d_in[4];
  const float* latent = (const float*)d_in[5];
  const float* cosT   = (const float*)d_in[6];
  const float* sinT   = (const float*)d_in[7];
  const int*   mask   = (const int*)d_in[8];

  char* ws = (char*)d_ws;
  __hip_bfloat16* xb = (__hip_bfloat16*)ws;                        // 33.5MB (reused as S)
  __hip_bfloat16* Wb = (__hip_bfloat16*)(ws + 33554432);           // 8.4MB
  __hip_bfloat16* qb = (__hip_bfloat16*)(ws + 41943040);           // 33.5MB (reused as attn)
  __hip_bfloat16* kb = (__hip_bfloat16*)(ws + 75497472);           // 33.5MB (reused as partials)
  __hip_bfloat16* kT = (__hip_bfloat16*)(ws + 109051904);          // 33.5MB [bh*64+d][t]
  __hip_bfloat16* vT = (__hip_bfloat16*)(ws + 142606336);          // 33.5MB
  char* tail = ws + 176160768;
  float* pmax = (float*)tail;                       // 131072 f
  float* psum = pmax + 131072;
  float* cmax = psum + 131072;                      // 4096 f
  float* cinv = cmax + 4096;
  __hip_bfloat16* k_lat  = (__hip_bfloat16*)(cinv + 4096);   // 262144 bf16
  __hip_bfloat16* v_latT = k_lat + 262144;

  __hip_bfloat16* S    = xb;                // xb dead after projection GEMMs
  __hip_bfloat16* attn = qb;                // qb dead after stage2 (in-place ok)
  float* partials = (float*)kb;             // kb dead after stage1_logits

  cvt_bf16<<<16384, 256, 0, stream>>>(x, xb, 16777216);
  cvt_bf16<<<1024, 256, 0, stream>>>(Wq, Wb + 0 * 1048576, 1048576);
  cvt_bf16<<<1024, 256, 0, stream>>>(Wk, Wb + 1 * 1048576, 1048576);
  cvt_bf16<<<1024, 256, 0, stream>>>(Wv, Wb + 2 * 1048576, 1048576);
  cvt_bf16<<<1024, 256, 0, stream>>>(Wo, Wb + 3 * 1048576, 1048576);

  dim3 gg(64, 4);
  gemm256<1, 1><<<gg, 512, 0, stream>>>(xb, Wb + 0 * 1048576, qb, nullptr, cosT, sinT, 16384, 1024, 1024);
  gemm256<2, 1><<<gg, 512, 0, stream>>>(xb, Wb + 1 * 1048576, kb, kT, cosT, sinT, 16384, 1024, 1024);
  gemm256<3, 0><<<gg, 512, 0, stream>>>(xb, Wb + 2 * 1048576, nullptr, vT, nullptr, nullptr, 16384, 1024, 1024);

  dim3 sg(64, 8);
  stage1_logits<<<sg, 256, 0, stream>>>(kb, latent, mask, S, pmax, psum);
  stage1_reduce<<<16, 256, 0, stream>>>(pmax, psum, cmax, cinv);

  dim3 lg(64, 4);
  latgemm5<<<lg, 256, 0, stream>>>(S, kT, vT, cmax, cinv, partials);
  latreduce<<<2048, 256, 0, stream>>>(partials, k_lat, v_latT);

  stage2_attn<<<4096, 256, 0, stream>>>(qb, k_lat, v_latT, attn);
  gemm256<0, 0><<<gg, 512, 0, stream>>>(attn, Wb + 3 * 1048576, d_out, nullptr, nullptr, nullptr, 16384, 1024, 1024);
}

// Round 8
// 321.861 us; speedup vs baseline: 2.0806x; 1.1187x over previous
//
#include <hip/hip_runtime.h>
#include <hip/hip_bf16.h>
#include <stdint.h>

// MLAAttention on MI355X (gfx950).
// B=4 T=4096 D=1024 H=16 M=64 Dh=64. All inputs f32 (mask int32), output f32.
// R8: gemm256 LDS XOR-swizzle (T2, rule #21): linear LDS dest (global_load_lds),
//     pre-swizzled GLOBAL source k-chunk (lane: (l&7)^(l>>3)), same XOR on the
//     ds_read (chunk ^ (lr&7)). Kills the 16-way bank conflict on the [row][64]
//     layout (R7 arithmetic: ~12.9k conflict-cy/step vs 9.75k wall).

#define DEV static __device__ __forceinline__

using short8 = __attribute__((ext_vector_type(8))) short;
using f32x4  = __attribute__((ext_vector_type(4))) float;

#define ZERO4 (f32x4){0.f, 0.f, 0.f, 0.f}

DEV float bf2f(unsigned short u) {
  union { unsigned int i; float f; } c; c.i = ((unsigned int)u) << 16; return c.f;
}
DEV unsigned short f2bf(float f) {
  __hip_bfloat16 h = __float2bfloat16(f);
  unsigned short u; __builtin_memcpy(&u, &h, 2); return u;
}
DEV f32x4 mfma16(short8 a, short8 b, f32x4 c) {
  return __builtin_amdgcn_mfma_f32_16x16x32_bf16(a, b, c, 0, 0, 0);
}
#define GLOAD_LDS16(G, L) __builtin_amdgcn_global_load_lds( \
    (const __attribute__((address_space(1))) void*)(G),     \
    (__attribute__((address_space(3))) void*)(L), 16, 0, 0)

// ---------------------------------------------------------------- convert
__global__ void cvt_bf16(const float* __restrict__ src,
                         __hip_bfloat16* __restrict__ dst, int n) {
  int i = (blockIdx.x * blockDim.x + threadIdx.x) * 4;
  if (i >= n) return;
  const float4 v = *(const float4*)(src + i);
  ushort4 o;
  o.x = f2bf(v.x); o.y = f2bf(v.y); o.z = f2bf(v.z); o.w = f2bf(v.w);
  *(ushort4*)(dst + i) = o;
}

// ---------------------------------------------------------------- GEMM 256x256
// C[M,N] = A[M,K] @ Bt[N,K]^T, bf16 in, f32 acc. 8 waves (2M x 4N), 2-phase
// double-buffered K-loop, counted vmcnt. LDS layout XOR-swizzled:
// element (row, chunk c of 8 bf16) lives at LDS (row, c ^ (row&7)).
// Staged via linear gload_lds dest + pre-swizzled global source (staging row&7
// = l>>3); read back with chunk ^ (lr&7) (fragment row&7 = lr&7).
// MODE: 0 = f32 normal; 1 = bf16 normal; 2 = bf16 normal + bf16 transposed;
//       3 = bf16 transposed only.
// ROPE: apply rotary (pairs along n; t = m&4095, d = n&63) to acc before stores.
// Transposed layout: Ct[((m>>12)*16 + (n>>6))*64 + (n&63)][t = m&4095]  (bf16)
template<int MODE, int ROPE>
__global__ __launch_bounds__(512, 2)
void gemm256(const __hip_bfloat16* __restrict__ A,
             const __hip_bfloat16* __restrict__ Bt,
             void* __restrict__ Cout, __hip_bfloat16* __restrict__ Ct,
             const float* __restrict__ cosT, const float* __restrict__ sinT,
             int M, int N, int K) {
  __shared__ __hip_bfloat16 As[2][256 * 64];
  __shared__ __hip_bfloat16 Bs[2][256 * 64];
  const int tid = threadIdx.x;
  const int w = tid >> 6, l = tid & 63;
  const int lr = l & 15, lg = l >> 4;
  const int rowA0 = blockIdx.x * 256;
  const int colB0 = blockIdx.y * 256;
  const int srow = w * 8 + (l >> 3);                 // staging row (row&7 = l>>3)
  const int skk  = (((l & 7) ^ (l >> 3)) * 8);       // pre-swizzled source k-chunk
  const __hip_bfloat16* Ab = A  + (size_t)(rowA0 + srow) * K + skk;
  const __hip_bfloat16* Bb = Bt + (size_t)(colB0 + srow) * K + skk;
  f32x4 acc[8][4];
#pragma unroll
  for (int i = 0; i < 8; ++i)
#pragma unroll
    for (int j = 0; j < 4; ++j) acc[i][j] = ZERO4;
  const int wr = (w >> 2) * 128;          // wave M-offset (0 or 128)
  const int wc = (w & 3) * 64;            // wave N-offset (0,64,128,192)
  const int NT = K >> 6;

#define G_STAGE(kt, buf)                                                          \
  {                                                                               \
    const int k0s = (kt) * 64;                                                    \
    _Pragma("unroll")                                                             \
    for (int i = 0; i < 4; ++i) {                                                 \
      GLOAD_LDS16(Ab + (size_t)(i * 64) * K + k0s, &As[buf][i * 4096 + w * 512]); \
      GLOAD_LDS16(Bb + (size_t)(i * 64) * K + k0s, &Bs[buf][i * 4096 + w * 512]); \
    }                                                                             \
  }

  G_STAGE(0, 0);
  for (int kt = 0; kt < NT; ++kt) {
    const int cur = kt & 1;
    if (kt + 1 < NT) {
      G_STAGE(kt + 1, cur ^ 1);                         // prefetch other slot
      asm volatile("s_waitcnt vmcnt(8)" ::: "memory");  // own stage(kt) landed
    } else {
      asm volatile("s_waitcnt vmcnt(0)" ::: "memory");
    }
    __builtin_amdgcn_s_barrier();                       // all waves' stage(kt) visible
    __builtin_amdgcn_s_setprio(1);
#pragma unroll
    for (int s = 0; s < 2; ++s) {
      short8 fa[8], fb[4];
#pragma unroll
      for (int i = 0; i < 8; ++i)
        fa[i] = *(const short8*)&As[cur][(wr + i * 16 + lr) * 64 +
                                         (((s * 4 + lg) ^ (lr & 7)) * 8)];
#pragma unroll
      for (int j = 0; j < 4; ++j)
        fb[j] = *(const short8*)&Bs[cur][(wc + j * 16 + lr) * 64 +
                                         (((s * 4 + lg) ^ (lr & 7)) * 8)];
#pragma unroll
      for (int i = 0; i < 8; ++i)
#pragma unroll
        for (int j = 0; j < 4; ++j)
          acc[i][j] = mfma16(fa[i], fb[j], acc[i][j]);
    }
    __builtin_amdgcn_s_setprio(0);
    __builtin_amdgcn_s_barrier();                       // slot reads done before restage
  }
#undef G_STAGE

  const int r0 = rowA0 + wr + lg * 4;     // global row (m) base, +i*16+r
  const int c0 = colB0 + wc + lr;         // global col (n), +j*16
  if (ROPE) {
#pragma unroll
    for (int i = 0; i < 8; ++i)
#pragma unroll
      for (int j = 0; j < 4; ++j)
#pragma unroll
        for (int r = 0; r < 4; ++r) {
          const int m = r0 + i * 16 + r;
          const int n = c0 + j * 16;
          const int t = m & 4095, d = n & 63;
          const float c = cosT[t * 64 + d];
          const float s = sinT[t * 64 + d];
          const float v = acc[i][j][r];
          const float other = __shfl_xor(v, 1, 64);
          acc[i][j][r] = v * c + ((n & 1) ? other : -other) * s;
        }
  }
  if (MODE <= 2) {
#pragma unroll
    for (int i = 0; i < 8; ++i)
#pragma unroll
      for (int j = 0; j < 4; ++j)
#pragma unroll
        for (int r = 0; r < 4; ++r) {
          const size_t idx = (size_t)(r0 + i * 16 + r) * N + (c0 + j * 16);
          if (MODE == 0) ((float*)Cout)[idx] = acc[i][j][r];
          else ((__hip_bfloat16*)Cout)[idx] = __float2bfloat16(acc[i][j][r]);
        }
  }
  if (MODE >= 2) {
#pragma unroll
    for (int i = 0; i < 8; ++i)
#pragma unroll
      for (int j = 0; j < 4; ++j) {
        const int m0 = r0 + i * 16;           // 4 contiguous t per lane
        const int n  = c0 + j * 16;
        const size_t row = (size_t)(((m0 >> 12) * 16 + (n >> 6)) * 64 + (n & 63));
        ushort4 pk;
        pk.x = f2bf(acc[i][j][0]); pk.y = f2bf(acc[i][j][1]);
        pk.z = f2bf(acc[i][j][2]); pk.w = f2bf(acc[i][j][3]);
        *(ushort4*)&Ct[row * 4096 + (m0 & 4095)] = pk;
      }
  }
}

// ---------------------------------------------------------------- stage1 logits (MFMA)
// S[bh][m][t] = 0.125 * sum_d latent[h][m][d]*K[b][t][h][d]  (bf16 store; -inf if masked)
// Fused online per-m (max,sum) partials: pmax/psum[(bh*8+chunk)*4 + wave][m].
__global__ __launch_bounds__(256)
void stage1_logits(const __hip_bfloat16* __restrict__ kmat,  // [B,T,H,64] (roped)
                   const float* __restrict__ latent,          // [H,64,64] f32
                   const int* __restrict__ mask,               // [B*T]
                   __hip_bfloat16* __restrict__ S,             // [bh][64][4096]
                   float* __restrict__ pmax, float* __restrict__ psum) {
  const int bh = blockIdx.x, chunk = blockIdx.y;
  const int b = bh >> 4, h = bh & 15;
  const int tid = threadIdx.x, w = tid >> 6, l = tid & 63;
  const int lr = l & 15, lg = l >> 4;
  short8 la[4][2];
#pragma unroll
  for (int n = 0; n < 4; ++n)
#pragma unroll
    for (int s = 0; s < 2; ++s) {
      const float* lp = &latent[((size_t)h * 64 + n * 16 + lr) * 64 + s * 32 + lg * 8];
      short8 f;
#pragma unroll
      for (int j = 0; j < 8; ++j) f[j] = (short)f2bf(lp[j]);
      la[n][s] = f;
    }
  float mx[16], sm[16];
#pragma unroll
  for (int i = 0; i < 16; ++i) { mx[i] = -3.0e38f; sm[i] = 0.f; }
  for (int tile = 0; tile < 8; ++tile) {
    const int t = chunk * 512 + tile * 64 + w * 16 + lr;
    const __hip_bfloat16* kp = &kmat[((size_t)(b * 4096 + t) * 16 + h) * 64 + lg * 8];
    const short8 kb0 = *(const short8*)kp;
    const short8 kb1 = *(const short8*)(kp + 32);
    const bool live = (mask[b * 4096 + t] != 0);
    f32x4 acc[4];
#pragma unroll
    for (int n = 0; n < 4; ++n) {
      acc[n] = ZERO4;
      acc[n] = mfma16(la[n][0], kb0, acc[n]);
      acc[n] = mfma16(la[n][1], kb1, acc[n]);
    }
#pragma unroll
    for (int n = 0; n < 4; ++n)
#pragma unroll
      for (int r = 0; r < 4; ++r) {
        const float v = acc[n][r] * 0.125f;
        const int m = n * 16 + lg * 4 + r;
        unsigned short sv = live ? f2bf(v) : (unsigned short)0xFF80;  // -inf
        ((unsigned short*)S)[((size_t)bh * 64 + m) * 4096 + t] = sv;
        if (live) {
          const int idx = n * 4 + r;
          const float nm = fmaxf(mx[idx], v);
          sm[idx] = sm[idx] * __expf(mx[idx] - nm) + __expf(v - nm);
          mx[idx] = nm;
        }
      }
  }
#pragma unroll
  for (int o = 1; o < 16; o <<= 1)
#pragma unroll
    for (int i = 0; i < 16; ++i) {
      const float omx = __shfl_xor(mx[i], o, 64);
      const float osm = __shfl_xor(sm[i], o, 64);
      const float nm = fmaxf(mx[i], omx);
      sm[i] = sm[i] * __expf(mx[i] - nm) + osm * __expf(omx - nm);
      mx[i] = nm;
    }
  if (lr == 0) {
    const size_t pb = ((size_t)(bh * 8 + chunk) * 4 + w) * 64;
#pragma unroll
    for (int n = 0; n < 4; ++n)
#pragma unroll
      for (int r = 0; r < 4; ++r) {
        const int m = n * 16 + lg * 4 + r;
        pmax[pb + m] = mx[n * 4 + r];
        psum[pb + m] = sm[n * 4 + r];
      }
  }
}

// combine 32 partials per (bh,m)
__global__ void stage1_reduce(const float* __restrict__ pmax,
                              const float* __restrict__ psum,
                              float* __restrict__ cmax, float* __restrict__ cinv) {
  const int i = blockIdx.x * 256 + threadIdx.x;
  if (i >= 4096) return;
  const int bh = i >> 6, m = i & 63;
  float mx = -3.0e38f;
#pragma unroll
  for (int c = 0; c < 32; ++c)
    mx = fmaxf(mx, pmax[((size_t)bh * 32 + c) * 64 + m]);
  float sm = 0.f;
#pragma unroll
  for (int c = 0; c < 32; ++c)
    sm += psum[((size_t)bh * 32 + c) * 64 + m] *
          __expf(pmax[((size_t)bh * 32 + c) * 64 + m] - mx);
  cmax[i] = mx;
  cinv[i] = 1.f / sm;
}

// ---------------------------------------------------------------- latent GEMM v5
// Direct-from-global register-fragment MFMA reduction with FUSED softmax-exp:
// fp = bf16(exp(S - cmax)*cinv) computed in-register from raw logits S.
// k_lat_part[m,d] = sum_t P[m,t]*kT[d,t]; v_latT_part[d,m] = sum_t vT[d,t]*P[m,t].
__global__ __launch_bounds__(256)
void latgemm5(const __hip_bfloat16* __restrict__ S,   // logits [bh][64][4096]
              const __hip_bfloat16* __restrict__ kT,
              const __hip_bfloat16* __restrict__ vT,
              const float* __restrict__ cmax, const float* __restrict__ cinv,
              float* __restrict__ partials) {   // [slice][bh][8192]
  const int bh = blockIdx.x;
  const int tid = threadIdx.x, w = tid >> 6, l = tid & 63;
  const int slice = blockIdx.y * 4 + w;
  const int lr = l & 15;            // frag row
  const int lk = (l >> 4) * 8;      // frag k-offset
  const size_t base = (size_t)bh * 64 * 4096;
  float cm[4], ci[4];
#pragma unroll
  for (int i = 0; i < 4; ++i) {
    cm[i] = cmax[bh * 64 + i * 16 + lr];
    ci[i] = cinv[bh * 64 + i * 16 + lr];
  }
  f32x4 ak[4][4], av[4][4];
#pragma unroll
  for (int i = 0; i < 4; ++i)
#pragma unroll
    for (int j = 0; j < 4; ++j) { ak[i][j] = ZERO4; av[i][j] = ZERO4; }
  for (int ks = 0; ks < 8; ++ks) {
    const int t = slice * 256 + ks * 32 + lk;
    short8 fp[4], fk[4], fv[4];
#pragma unroll
    for (int i = 0; i < 4; ++i) {
      const size_t ro = base + (size_t)(i * 16 + lr) * 4096 + t;
      const short8 sv = *(const short8*)&S[ro];
      short8 p;
#pragma unroll
      for (int j = 0; j < 8; ++j)
        p[j] = (short)f2bf(__expf(bf2f((unsigned short)sv[j]) - cm[i]) * ci[i]);
      fp[i] = p;
      fk[i] = *(const short8*)&kT[ro];
      fv[i] = *(const short8*)&vT[ro];
    }
#pragma unroll
    for (int i = 0; i < 4; ++i)
#pragma unroll
      for (int j = 0; j < 4; ++j) {
        ak[i][j] = mfma16(fp[i], fk[j], ak[i][j]);   // C[m][d]
        av[i][j] = mfma16(fv[i], fp[j], av[i][j]);   // C[d][m]
      }
  }
  float* pk = partials + ((size_t)(slice * 64 + bh)) * 8192;
#pragma unroll
  for (int i = 0; i < 4; ++i)
#pragma unroll
    for (int j = 0; j < 4; ++j)
#pragma unroll
      for (int r = 0; r < 4; ++r) {
        const int row = i * 16 + 4 * (l >> 4) + r;
        const int col = j * 16 + lr;
        pk[(size_t)row * 64 + col]        = ak[i][j][r];
        pk[4096 + (size_t)row * 64 + col] = av[i][j][r];
      }
}

// Sum 16 slice-partials -> bf16 k_lat [bh][m][d] and v_latT [bh][d][m]
__global__ void latreduce(const float* __restrict__ partials,
                          __hip_bfloat16* __restrict__ k_lat,
                          __hip_bfloat16* __restrict__ v_latT) {
  const int i = blockIdx.x * 256 + threadIdx.x;   // 524288
  const int bh = i >> 13, off = i & 8191;
  float sm = 0.f;
#pragma unroll
  for (int c = 0; c < 16; ++c)
    sm += partials[((size_t)(c * 64 + bh)) * 8192 + off];
  if (off < 4096) k_lat[(size_t)bh * 4096 + off] = __float2bfloat16(sm);
  else            v_latT[(size_t)bh * 4096 + (off - 4096)] = __float2bfloat16(sm);
}

// ---------------------------------------------------------------- stage2 fused
__global__ __launch_bounds__(256)
void stage2_attn(const __hip_bfloat16* __restrict__ q,
                 const __hip_bfloat16* __restrict__ k_lat,
                 const __hip_bfloat16* __restrict__ v_latT,
                 __hip_bfloat16* __restrict__ attn) {
  __shared__ unsigned short Pl[4][16][64];
  const int bid = blockIdx.x;
  const int bh = bid >> 6, tt = (bid & 63) * 64;
  const int b = bh >> 4, h = bh & 15;
  const int tid = threadIdx.x, w = tid >> 6, l = tid & 63;
  const size_t qoff = ((size_t)(b * 4096 + tt + w * 16 + (l & 15)) * 16 + h) * 64;
  const short8 a0 = *(const short8*)&q[qoff + (l >> 4) * 8];
  const short8 a1 = *(const short8*)&q[qoff + 32 + (l >> 4) * 8];
  f32x4 att[4];
#pragma unroll
  for (int n = 0; n < 4; ++n) att[n] = ZERO4;
#pragma unroll
  for (int n = 0; n < 4; ++n) {
    const __hip_bfloat16* kl = &k_lat[((size_t)bh * 64 + n * 16 + (l & 15)) * 64];
    const short8 b0 = *(const short8*)&kl[(l >> 4) * 8];
    const short8 b1 = *(const short8*)&kl[32 + (l >> 4) * 8];
    att[n] = mfma16(a0, b0, att[n]);
    att[n] = mfma16(a1, b1, att[n]);
  }
  float p[4][4];
#pragma unroll
  for (int r = 0; r < 4; ++r) {
    const float v0 = att[0][r] * 0.125f, v1 = att[1][r] * 0.125f;
    const float v2 = att[2][r] * 0.125f, v3 = att[3][r] * 0.125f;
    float mxv = fmaxf(fmaxf(v0, v1), fmaxf(v2, v3));
#pragma unroll
    for (int o = 1; o < 16; o <<= 1) mxv = fmaxf(mxv, __shfl_xor(mxv, o, 64));
    const float e0 = __expf(v0 - mxv), e1 = __expf(v1 - mxv);
    const float e2 = __expf(v2 - mxv), e3 = __expf(v3 - mxv);
    float sum = e0 + e1 + e2 + e3;
#pragma unroll
    for (int o = 1; o < 16; o <<= 1) sum += __shfl_xor(sum, o, 64);
    const float inv = 1.f / sum;
    p[0][r] = e0 * inv; p[1][r] = e1 * inv; p[2][r] = e2 * inv; p[3][r] = e3 * inv;
  }
#pragma unroll
  for (int n = 0; n < 4; ++n)
#pragma unroll
    for (int r = 0; r < 4; ++r) {
      const int row = 4 * (l >> 4) + r;
      const int col = n * 16 + (l & 15);
      Pl[w][row][col ^ ((row & 7) << 3)] = f2bf(p[n][r]);
    }
  __syncthreads();
  const int arow = l & 15;
  const short8 pa0 = *(const short8*)&Pl[w][arow][(((l >> 4) + 0) ^ (arow & 7)) * 8];
  const short8 pa1 = *(const short8*)&Pl[w][arow][(((l >> 4) + 4) ^ (arow & 7)) * 8];
  f32x4 ov[4];
#pragma unroll
  for (int n = 0; n < 4; ++n) ov[n] = ZERO4;
#pragma unroll
  for (int n = 0; n < 4; ++n) {
    const __hip_bfloat16* vt = &v_latT[((size_t)bh * 64 + n * 16 + (l & 15)) * 64];
    const short8 b0 = *(const short8*)&vt[(l >> 4) * 8];
    const short8 b1 = *(const short8*)&vt[32 + (l >> 4) * 8];
    ov[n] = mfma16(pa0, b0, ov[n]);
    ov[n] = mfma16(pa1, b1, ov[n]);
  }
#pragma unroll
  for (int n = 0; n < 4; ++n) {
    const int d = n * 16 + (l & 15);
#pragma unroll
    for (int r = 0; r < 4; ++r) {
      const int trow = tt + w * 16 + 4 * (l >> 4) + r;
      attn[((size_t)(b * 4096 + trow) * 16 + h) * 64 + d] = __float2bfloat16(ov[n][r]);
    }
  }
}

// ---------------------------------------------------------------- launch
extern "C" void kernel_launch(void* const* d_in, const int* in_sizes, int n_in,
                              void* d_out, int out_size, void* d_ws, size_t ws_size,
                              hipStream_t stream) {
  const float* x      = (const float*)d_in[0];
  const float* Wq     = (const float*)d_in[1];
  const float* Wk     = (const float*)d_in[2];
  const float* Wv     = (const float*)d_in[3];
  const float* Wo     = (const float*)d_in[4];
  const float* latent = (const float*)d_in[5];
  const float* cosT   = (const float*)d_in[6];
  const float* sinT   = (const float*)d_in[7];
  const int*   mask   = (const int*)d_in[8];

  char* ws = (char*)d_ws;
  __hip_bfloat16* xb = (__hip_bfloat16*)ws;                        // 33.5MB (reused as S)
  __hip_bfloat16* Wb = (__hip_bfloat16*)(ws + 33554432);           // 8.4MB
  __hip_bfloat16* qb = (__hip_bfloat16*)(ws + 41943040);           // 33.5MB (reused as attn)
  __hip_bfloat16* kb = (__hip_bfloat16*)(ws + 75497472);           // 33.5MB (reused as partials)
  __hip_bfloat16* kT = (__hip_bfloat16*)(ws + 109051904);          // 33.5MB [bh*64+d][t]
  __hip_bfloat16* vT = (__hip_bfloat16*)(ws + 142606336);          // 33.5MB
  char* tail = ws + 176160768;
  float* pmax = (float*)tail;                       // 131072 f
  float* psum = pmax + 131072;
  float* cmax = psum + 131072;                      // 4096 f
  float* cinv = cmax + 4096;
  __hip_bfloat16* k_lat  = (__hip_bfloat16*)(cinv + 4096);   // 262144 bf16
  __hip_bfloat16* v_latT = k_lat + 262144;

  __hip_bfloat16* S    = xb;                // xb dead after projection GEMMs
  __hip_bfloat16* attn = qb;                // qb dead after stage2 (in-place ok)
  float* partials = (float*)kb;             // kb dead after stage1_logits

  cvt_bf16<<<16384, 256, 0, stream>>>(x, xb, 16777216);
  cvt_bf16<<<1024, 256, 0, stream>>>(Wq, Wb + 0 * 1048576, 1048576);
  cvt_bf16<<<1024, 256, 0, stream>>>(Wk, Wb + 1 * 1048576, 1048576);
  cvt_bf16<<<1024, 256, 0, stream>>>(Wv, Wb + 2 * 1048576, 1048576);
  cvt_bf16<<<1024, 256, 0, stream>>>(Wo, Wb + 3 * 1048576, 1048576);

  dim3 gg(64, 4);
  gemm256<1, 1><<<gg, 512, 0, stream>>>(xb, Wb + 0 * 1048576, qb, nullptr, cosT, sinT, 16384, 1024, 1024);
  gemm256<2, 1><<<gg, 512, 0, stream>>>(xb, Wb + 1 * 1048576, kb, kT, cosT, sinT, 16384, 1024, 1024);
  gemm256<3, 0><<<gg, 512, 0, stream>>>(xb, Wb + 2 * 1048576, nullptr, vT, nullptr, nullptr, 16384, 1024, 1024);

  dim3 sg(64, 8);
  stage1_logits<<<sg, 256, 0, stream>>>(kb, latent, mask, S, pmax, psum);
  stage1_reduce<<<16, 256, 0, stream>>>(pmax, psum, cmax, cinv);

  dim3 lg(64, 4);
  latgemm5<<<lg, 256, 0, stream>>>(S, kT, vT, cmax, cinv, partials);
  latreduce<<<2048, 256, 0, stream>>>(partials, k_lat, v_latT);

  stage2_attn<<<4096, 256, 0, stream>>>(qb, k_lat, v_latT, attn);
  gemm256<0, 0><<<gg, 512, 0, stream>>>(attn, Wb + 3 * 1048576, d_out, nullptr, nullptr, nullptr, 16384, 1024, 1024);
}